// Round 1
// baseline (632.444 us; speedup 1.0000x reference)
//
#include <hip/hip_runtime.h>
#include <math.h>

#define TPB 256

typedef float2 cf;

__device__ __forceinline__ cf cmk(float x, float y){ cf r; r.x=x; r.y=y; return r; }
__device__ __forceinline__ cf cml(cf a, cf b){ return cmk(a.x*b.x - a.y*b.y, a.x*b.y + a.y*b.x); }
__device__ __forceinline__ cf cad(cf a, cf b){ return cmk(a.x+b.x, a.y+b.y); }
__device__ __forceinline__ cf csb(cf a, cf b){ return cmk(a.x-b.x, a.y-b.y); }
__device__ __forceinline__ cf crcp(cf d){ float r = 1.0f/(d.x*d.x + d.y*d.y); return cmk(d.x*r, -d.y*r); }
__device__ __forceinline__ cf cdv(cf n, cf d){ return cml(n, crcp(d)); }
__device__ __forceinline__ float geluf(float z){ return 0.5f*z*(1.0f + erff(z*0.70710678118654752f)); }

// ---------------- FFT primitives (in-place, LDS, 256 threads) ----------------
// DIF: natural order in -> bit-reversed order out. X[k] = sum x[n] e^{sign*2pi i k n/N}
template<int N>
__device__ void fft_dif(cf* a, float sign){
  for (int s = N >> 1; s >= 1; s >>= 1){
    __syncthreads();
    for (int w = threadIdx.x; w < (N >> 1); w += TPB){
      int k = w & (s - 1);
      int i = ((w & ~(s - 1)) << 1) | k;
      cf u = a[i], v = a[i + s];
      float sp, cp;
      sincospif((float)k / (float)s, &sp, &cp);
      cf tw = cmk(cp, sign * sp);
      a[i]     = cad(u, v);
      a[i + s] = cml(csb(u, v), tw);
    }
  }
  __syncthreads();
}

// DIT: bit-reversed order in -> natural order out.
template<int N>
__device__ void fft_dit(cf* a, float sign){
  for (int s = 1; s < N; s <<= 1){
    __syncthreads();
    for (int w = threadIdx.x; w < (N >> 1); w += TPB){
      int k = w & (s - 1);
      int i = ((w & ~(s - 1)) << 1) | k;
      cf u = a[i], v = a[i + s];
      float sp, cp;
      sincospif((float)k / (float)s, &sp, &cp);
      cf tw = cmk(cp, sign * sp);
      v = cml(v, tw);
      a[i]     = cad(u, v);
      a[i + s] = csb(u, v);
    }
  }
  __syncthreads();
}

// ---------------- init atomic-max buffers ----------------
__global__ void k_init(unsigned* xmax, unsigned* ymax){
  int i = blockIdx.x * 256 + threadIdx.x;
  if (i < 2048){ xmax[i] = 0u; ymax[i] = 0u; }
}

// ---------------- transpose x (B,L,H)->(B,H,L), fused max|x| over t ----------------
__global__ __launch_bounds__(256) void k_transpose_x(const float* __restrict__ x,
                                                     float* __restrict__ xT,
                                                     unsigned* __restrict__ xmax){
  __shared__ float tile[64][65];
  __shared__ float red[64][4];
  int b = blockIdx.z;
  int t0 = blockIdx.x * 64;
  int h0 = blockIdx.y * 64;
  int hc = threadIdx.x & 63, tg = threadIdx.x >> 6;
  float pmax = 0.0f;
  #pragma unroll
  for (int q = 0; q < 16; q++){
    int tr = tg + q * 4;
    float v = x[((size_t)(b * 4096 + t0 + tr)) * 256 + h0 + hc];
    tile[tr][hc] = v;
    pmax = fmaxf(pmax, fabsf(v));
  }
  red[hc][tg] = pmax;
  __syncthreads();
  if (threadIdx.x < 64){
    float m = fmaxf(fmaxf(red[threadIdx.x][0], red[threadIdx.x][1]),
                    fmaxf(red[threadIdx.x][2], red[threadIdx.x][3]));
    atomicMax(&xmax[b * 256 + h0 + threadIdx.x], __float_as_uint(m));
  }
  #pragma unroll
  for (int q = 0; q < 16; q++){
    int hr = tg + q * 4;
    xT[((size_t)(b * 256 + h0 + hr)) * 4096 + t0 + hc] = tile[hc][hr];
  }
}

// ---------------- transpose W (256x256) ----------------
__global__ __launch_bounds__(256) void k_wtrans(const float* __restrict__ W, float* __restrict__ WT){
  __shared__ float tile[64][65];
  int j0 = blockIdx.x * 64, k0 = blockIdx.y * 64;
  int c = threadIdx.x & 63, rg = threadIdx.x >> 6;
  #pragma unroll
  for (int q = 0; q < 16; q++){
    int r = rg + q * 4;
    tile[r][c] = W[(j0 + r) * 256 + k0 + c];
  }
  __syncthreads();
  #pragma unroll
  for (int q = 0; q < 16; q++){
    int r = rg + q * 4;
    WT[(k0 + r) * 256 + j0 + c] = tile[c][r];
  }
}

// ---------------- Cauchy / generating function: atRoots (H=256, L=4096) ----------------
__global__ __launch_bounds__(256) void k_cauchy(
    const float* __restrict__ Lr, const float* __restrict__ Li,
    const float* __restrict__ Pr, const float* __restrict__ Pi,
    const float* __restrict__ Qr, const float* __restrict__ Qi,
    const float* __restrict__ Br, const float* __restrict__ Bi,
    const float* __restrict__ Cr, const float* __restrict__ Ci,
    const float* __restrict__ stepp, cf* __restrict__ A)
{
  __shared__ cf sLam[64], sB[64], sP[64], sQB[64], sQP[64];
  __shared__ cf sInv[64][16];   // [n][l]
  __shared__ cf sWood[16], sC[16], sG[16];
  int tid = threadIdx.x;
  int l0 = blockIdx.x * 16;
  float stepv = fmaxf(stepp[0], 1e-6f);
  if (tid < 64){
    cf lam = cmk(Lr[tid], Li[tid]);
    cf b = cmk(Br[tid], Bi[tid]);
    cf p = cmk(Pr[tid], Pi[tid]);
    cf q = cmk(Qr[tid], Qi[tid]);
    sLam[tid] = lam; sB[tid] = b; sP[tid] = p;
    sQB[tid] = cml(q, b);
    sQP[tid] = cml(q, p);
  }
  __syncthreads();
  if (tid < 16){
    int l = l0 + tid;
    // match JAX float32: ang = f32(-2*pi) * (l/L); sinf/cosf precise (nonzero at l=L/2)
    float ang = -6.2831855f * ((float)l * (1.0f / 4096.0f));
    cf Om = cmk(cosf(ang), sinf(ang));
    cf den = cmk(1.0f + Om.x, Om.y);
    cf num = cmk(1.0f - Om.x, -Om.y);
    cf rden = crcp(den);
    sC[tid] = cml(cmk(2.0f, 0.0f), rden);
    cf g = cml(num, rden);
    float sc = 2.0f / stepv;
    sG[tid] = cmk(g.x * sc, g.y * sc);
  }
  __syncthreads();
  for (int it = tid; it < 1024; it += 256){
    int n = it >> 4, ll = it & 15;
    sInv[n][ll] = crcp(csb(sG[ll], sLam[n]));
  }
  __syncthreads();
  if (tid < 16){
    cf k10 = cmk(0,0), k11 = cmk(0,0);
    for (int n = 0; n < 64; n++){
      k10 = cad(k10, cml(sQB[n], sInv[n][tid]));
      k11 = cad(k11, cml(sQP[n], sInv[n][tid]));
    }
    sWood[tid] = cdv(k10, cmk(1.0f + k11.x, k11.y));
  }
  __syncthreads();
  int h = tid;
  cf a0[16], a1[16];
  #pragma unroll
  for (int ll = 0; ll < 16; ll++){ a0[ll] = cmk(0,0); a1[ll] = cmk(0,0); }
  for (int n = 0; n < 64; n++){
    cf cc = cmk(Cr[h * 64 + n], Ci[h * 64 + n]);
    cf cb = cml(cc, sB[n]);
    cf cp = cml(cc, sP[n]);
    #pragma unroll
    for (int ll = 0; ll < 16; ll++){
      cf iv = sInv[n][ll];
      a0[ll] = cad(a0[ll], cml(cb, iv));
      a1[ll] = cad(a1[ll], cml(cp, iv));
    }
  }
  cf* dst = A + (size_t)h * 4096 + l0;
  #pragma unroll
  for (int ll = 0; ll < 16; ll++){
    dst[ll] = cml(sC[ll], csb(a0[ll], cml(a1[ll], sWood[ll])));
  }
}

// ---------------- K kernel: atRoots -> ifft_4096 -> real -> fft_8192 (bit-rev order) ----------------
__global__ __launch_bounds__(256) void k_kf(const cf* __restrict__ A, cf* __restrict__ Kf){
  extern __shared__ cf c[];
  int h = blockIdx.x, tid = threadIdx.x;
  const cf* ah = A + (size_t)h * 4096;
  for (int l = tid; l < 4096; l += 256){
    int r = (int)(__brev((unsigned)l) >> 20);   // 12-bit reverse
    c[r] = ah[l];
  }
  fft_dit<4096>(c, 1.0f);                        // ifft (unscaled), natural order
  float kr[16];
  #pragma unroll
  for (int q = 0; q < 16; q++) kr[q] = c[tid + q * 256].x * (1.0f / 4096.0f);
  __syncthreads();
  #pragma unroll
  for (int q = 0; q < 16; q++){
    c[tid + q * 256]        = cmk(kr[q], 0.0f);  // K, zero-padded to 8192
    c[tid + q * 256 + 4096] = cmk(0.0f, 0.0f);
  }
  fft_dif<8192>(c, -1.0f);                       // Kf in 13-bit-reversed order
  cf* kf = Kf + (size_t)h * 8192;
  for (int i = tid; i < 8192; i += 256) kf[i] = c[i];
}

// ---------------- conv: per (b,h): fft(x pad) * Kf -> ifft -> gelu(h1 + D*x) ----------------
__global__ __launch_bounds__(256) void k_conv(const float* __restrict__ xT,
                                              const cf* __restrict__ Kf,
                                              const float* __restrict__ Dp,
                                              float* __restrict__ y1T){
  extern __shared__ cf c[];
  int bh = blockIdx.x, tid = threadIdx.x;
  int h = bh & 255;
  const float* xs = xT + (size_t)bh * 4096;
  for (int t = tid; t < 4096; t += 256){
    c[t]        = cmk(xs[t], 0.0f);
    c[t + 4096] = cmk(0.0f, 0.0f);
  }
  fft_dif<8192>(c, -1.0f);
  const cf* kf = Kf + (size_t)h * 8192;
  for (int i = tid; i < 8192; i += 256) c[i] = cml(c[i], kf[i]);
  fft_dit<8192>(c, 1.0f);
  float Dv = Dp[0];
  float* yd = y1T + (size_t)bh * 4096;
  for (int t = tid; t < 4096; t += 256){
    float h1 = c[t].x * (1.0f / 8192.0f);
    yd[t] = geluf(fmaf(Dv, xs[t], h1));
  }
}

// ---------------- GEMM (y1 @ W^T + b) + gelu + skip + LayerNorm + max|y| ----------------
__global__ __launch_bounds__(256) void k_gemm_ln(
    const float* __restrict__ y1T, const float* __restrict__ WT,
    const float* __restrict__ bfc, const float* __restrict__ x,
    const float* __restrict__ lng, const float* __restrict__ lnb,
    float* __restrict__ yout, unsigned* __restrict__ ymax)
{
  __shared__ float ytile[32][64];
  __shared__ float wtile[32][256];
  __shared__ float red[256][4];
  int tid = threadIdx.x;
  int b  = blockIdx.x >> 6;
  int t0 = (blockIdx.x & 63) << 6;
  int jg = tid & 63;     // owns j = jg*4 + jj
  int tg = tid >> 6;     // owns t = t0 + tg*16 + ti  (wave index == tg)
  float acc[4][16];
  #pragma unroll
  for (int jj = 0; jj < 4; jj++)
    #pragma unroll
    for (int ti = 0; ti < 16; ti++) acc[jj][ti] = 0.0f;

  int kk = tid >> 3, seg = tid & 7;
  for (int kc = 0; kc < 256; kc += 32){
    __syncthreads();
    const float* ysrc = y1T + ((size_t)(b * 256 + kc + kk)) * 4096 + t0 + seg * 8;
    float4 ya = *(const float4*)(ysrc);
    float4 yb = *(const float4*)(ysrc + 4);
    *(float4*)&ytile[kk][seg * 8]     = ya;
    *(float4*)&ytile[kk][seg * 8 + 4] = yb;
    const float* wsrc = WT + (size_t)(kc + kk) * 256 + seg * 32;
    #pragma unroll
    for (int q = 0; q < 8; q++)
      *(float4*)&wtile[kk][seg * 32 + q * 4] = *(const float4*)(wsrc + q * 4);
    __syncthreads();
    #pragma unroll 4
    for (int k2 = 0; k2 < 32; k2++){
      float4 wv  = *(const float4*)&wtile[k2][jg * 4];
      float4 q0  = *(const float4*)&ytile[k2][tg * 16];
      float4 q1  = *(const float4*)&ytile[k2][tg * 16 + 4];
      float4 q2  = *(const float4*)&ytile[k2][tg * 16 + 8];
      float4 q3  = *(const float4*)&ytile[k2][tg * 16 + 12];
      float yv[16];
      *(float4*)&yv[0]  = q0; *(float4*)&yv[4]  = q1;
      *(float4*)&yv[8]  = q2; *(float4*)&yv[12] = q3;
      float wa[4] = {wv.x, wv.y, wv.z, wv.w};
      #pragma unroll
      for (int jj = 0; jj < 4; jj++)
        #pragma unroll
        for (int ti = 0; ti < 16; ti++)
          acc[jj][ti] = fmaf(wa[jj], yv[ti], acc[jj][ti]);
    }
  }

  float4 bv = *(const float4*)&bfc[jg * 4];
  float4 gv = *(const float4*)&lng[jg * 4];
  float4 lv = *(const float4*)&lnb[jg * 4];
  float ba[4] = {bv.x, bv.y, bv.z, bv.w};
  float ga[4] = {gv.x, gv.y, gv.z, gv.w};
  float la[4] = {lv.x, lv.y, lv.z, lv.w};

  float psum[16], psq[16];
  #pragma unroll
  for (int ti = 0; ti < 16; ti++){ psum[ti] = 0.0f; psq[ti] = 0.0f; }
  #pragma unroll
  for (int ti = 0; ti < 16; ti++){
    int t = t0 + tg * 16 + ti;
    float4 xv = *(const float4*)&x[((size_t)(b * 4096 + t)) * 256 + jg * 4];
    float xa[4] = {xv.x, xv.y, xv.z, xv.w};
    #pragma unroll
    for (int jj = 0; jj < 4; jj++){
      float zz = geluf(acc[jj][ti] + ba[jj]) + xa[jj];
      acc[jj][ti] = zz;
      psum[ti] += zz;
      psq[ti] = fmaf(zz, zz, psq[ti]);
    }
  }
  // wave-wide butterfly reduce across the 64 jg lanes (tg is wave-uniform)
  #pragma unroll
  for (int m = 1; m < 64; m <<= 1){
    #pragma unroll
    for (int ti = 0; ti < 16; ti++){
      psum[ti] += __shfl_xor(psum[ti], m);
      psq[ti]  += __shfl_xor(psq[ti], m);
    }
  }
  float ymx[4] = {0.0f, 0.0f, 0.0f, 0.0f};
  #pragma unroll
  for (int ti = 0; ti < 16; ti++){
    float mu  = psum[ti] * (1.0f / 256.0f);
    float var = psq[ti] * (1.0f / 256.0f) - mu * mu;
    float rstd = rsqrtf(var + 1e-5f);
    int t = t0 + tg * 16 + ti;
    float4 o;
    float oa[4];
    #pragma unroll
    for (int jj = 0; jj < 4; jj++){
      float yv2 = (acc[jj][ti] - mu) * rstd * ga[jj] + la[jj];
      oa[jj] = yv2;
      ymx[jj] = fmaxf(ymx[jj], fabsf(yv2));
    }
    o.x = oa[0]; o.y = oa[1]; o.z = oa[2]; o.w = oa[3];
    *(float4*)&yout[((size_t)(b * 4096 + t)) * 256 + jg * 4] = o;
  }
  __syncthreads();
  #pragma unroll
  for (int jj = 0; jj < 4; jj++) red[jg * 4 + jj][tg] = ymx[jj];
  __syncthreads();
  {
    float m = fmaxf(fmaxf(red[tid][0], red[tid][1]), fmaxf(red[tid][2], red[tid][3]));
    atomicMax(&ymax[b * 256 + tid], __float_as_uint(m));
  }
}

// ---------------- final ratio ----------------
__global__ void k_ratio(const unsigned* __restrict__ ymax, const unsigned* __restrict__ xmax,
                        float* __restrict__ out){
  int i = blockIdx.x * 256 + threadIdx.x;
  if (i < 2048){
    float ym = __uint_as_float(ymax[i]);
    float xm = __uint_as_float(xmax[i]);
    out[8388608 + i] = ym / (xm + 1e-6f);
  }
}

extern "C" void kernel_launch(void* const* d_in, const int* in_sizes, int n_in,
                              void* d_out, int out_size, void* d_ws, size_t ws_size,
                              hipStream_t stream)
{
  const float* x    = (const float*)d_in[0];
  const float* Lr   = (const float*)d_in[1];
  const float* Li   = (const float*)d_in[2];
  const float* Pr   = (const float*)d_in[3];
  const float* Pi   = (const float*)d_in[4];
  const float* Qr   = (const float*)d_in[5];
  const float* Qi   = (const float*)d_in[6];
  const float* Br   = (const float*)d_in[7];
  const float* Bi   = (const float*)d_in[8];
  const float* Cr   = (const float*)d_in[9];
  const float* Ci   = (const float*)d_in[10];
  const float* stp  = (const float*)d_in[11];
  const float* Dp   = (const float*)d_in[12];
  const float* Wfc  = (const float*)d_in[13];
  const float* bfc  = (const float*)d_in[14];
  const float* lng  = (const float*)d_in[15];
  const float* lnb  = (const float*)d_in[16];

  char* ws = (char*)d_ws;
  float*    xT   = (float*)(ws);                                   // 32 MB
  cf*       Kf   = (cf*)(ws + ((size_t)32 << 20));                 // 16 MB
  float*    y1T  = (float*)(ws + ((size_t)48 << 20));              // 32 MB
  cf*       A    = (cf*)(ws + ((size_t)48 << 20));                 // 8 MB overlay (dead before y1T written)
  float*    WT   = (float*)(ws + ((size_t)80 << 20));              // 256 KB
  unsigned* xmax = (unsigned*)(ws + ((size_t)80 << 20) + (256u << 10));
  unsigned* ymax = xmax + 2048;

  k_init<<<8, 256, 0, stream>>>(xmax, ymax);
  dim3 gt(64, 4, 8);
  k_transpose_x<<<gt, 256, 0, stream>>>(x, xT, xmax);
  k_wtrans<<<dim3(4, 4), 256, 0, stream>>>(Wfc, WT);
  k_cauchy<<<256, 256, 0, stream>>>(Lr, Li, Pr, Pi, Qr, Qi, Br, Bi, Cr, Ci, stp, A);
  k_kf<<<256, 256, 65536, stream>>>(A, Kf);
  k_conv<<<2048, 256, 65536, stream>>>(xT, Kf, Dp, y1T);
  k_gemm_ln<<<512, 256, 0, stream>>>(y1T, WT, bfc, x, lng, lnb, (float*)d_out, ymax);
  k_ratio<<<8, 256, 0, stream>>>(ymax, xmax, (float*)d_out);
}

// Round 2
// 275.418 us; speedup vs baseline: 2.2963x; 2.2963x over previous
//
#include <hip/hip_runtime.h>
#include <math.h>

#define TPB 256

typedef float2 cf;

__device__ __forceinline__ cf cmk(float x, float y){ cf r; r.x=x; r.y=y; return r; }
__device__ __forceinline__ cf cml(cf a, cf b){ return cmk(a.x*b.x - a.y*b.y, a.x*b.y + a.y*b.x); }
__device__ __forceinline__ cf cad(cf a, cf b){ return cmk(a.x+b.x, a.y+b.y); }
__device__ __forceinline__ cf csb(cf a, cf b){ return cmk(a.x-b.x, a.y-b.y); }
__device__ __forceinline__ cf crcp(cf d){ float r = 1.0f/(d.x*d.x + d.y*d.y); return cmk(d.x*r, -d.y*r); }
__device__ __forceinline__ cf cdv(cf n, cf d){ return cml(n, crcp(d)); }
__device__ __forceinline__ float geluf(float z){ return 0.5f*z*(1.0f + erff(z*0.70710678118654752f)); }

// ---------------- radix-4 FFT primitives (in-place, LDS, 256 threads) ----------------
// Transform: X[k] = sum_n x[n] e^{sign*2pi i n k / N}. DIF: natural->bitrev. DIT: bitrev->natural.

template<int N, int SSTART>
__device__ void fft_dif_r4(cf* __restrict__ a, float sign){
  #pragma unroll
  for (int s = SSTART; s >= 1; s >>= 2){
    __syncthreads();
    #pragma unroll
    for (int g = 0; g < (N >> 2) / TPB; g++){
      int w = (int)threadIdx.x + g * TPB;
      int j = w & (s - 1);
      int base = ((w & ~(s - 1)) << 2) | j;
      cf A0 = a[base], B0 = a[base + s], C0 = a[base + 2*s], D0 = a[base + 3*s];
      float sp, cp;
      sincospif((float)j / (float)(2 * s), &sp, &cp);
      cf w1 = cmk(cp, sign * sp);          // W(j, 2s)
      cf w2 = cml(w1, w1);                 // W(j, s)
      cf a1 = cad(A0, C0);
      cf c1 = cml(csb(A0, C0), w1);
      cf b1 = cad(B0, D0);
      cf d1 = cml(csb(B0, D0), cmk(-sign * w1.y, sign * w1.x));  // * W(j+s,2s) = w1*sign*i
      a[base]         = cad(a1, b1);
      a[base + s]     = cml(csb(a1, b1), w2);
      a[base + 2*s]   = cad(c1, d1);
      a[base + 3*s]   = cml(csb(c1, d1), w2);
    }
  }
  if constexpr ((__builtin_ctz(N) & 1) == 1){   // trailing radix-2, span 1, twiddle 1
    __syncthreads();
    #pragma unroll
    for (int g = 0; g < (N >> 1) / TPB; g++){
      int w = (int)threadIdx.x + g * TPB;
      int i = w << 1;
      cf u = a[i], v = a[i + 1];
      a[i] = cad(u, v);
      a[i + 1] = csb(u, v);
    }
  }
  __syncthreads();
}

template<int N>
__device__ void fft_dit_r4(cf* __restrict__ a, float sign){
  if constexpr ((__builtin_ctz(N) & 1) == 1){   // leading radix-2, span 1, twiddle 1
    __syncthreads();
    #pragma unroll
    for (int g = 0; g < (N >> 1) / TPB; g++){
      int w = (int)threadIdx.x + g * TPB;
      int i = w << 1;
      cf u = a[i], v = a[i + 1];
      a[i] = cad(u, v);
      a[i + 1] = csb(u, v);
    }
  }
  constexpr int S0 = ((__builtin_ctz(N) & 1) == 1) ? 2 : 1;
  #pragma unroll
  for (int s = S0; s <= (N >> 2); s <<= 2){
    __syncthreads();
    #pragma unroll
    for (int g = 0; g < (N >> 2) / TPB; g++){
      int w = (int)threadIdx.x + g * TPB;
      int j = w & (s - 1);
      int base = ((w & ~(s - 1)) << 2) | j;
      cf A0 = a[base], B0 = a[base + s], C0 = a[base + 2*s], D0 = a[base + 3*s];
      float sp, cp;
      sincospif((float)j / (float)(2 * s), &sp, &cp);
      cf w1 = cmk(cp, sign * sp);
      cf w2 = cml(w1, w1);
      cf t1 = cml(B0, w2);
      cf a1 = cad(A0, t1), b1 = csb(A0, t1);
      cf t2 = cml(D0, w2);
      cf c1 = cad(C0, t2), d1 = csb(C0, t2);
      cf v1 = cml(c1, w1);
      cf v2 = cml(d1, cmk(-sign * w1.y, sign * w1.x));
      a[base]         = cad(a1, v1);
      a[base + 2*s]   = csb(a1, v1);
      a[base + s]     = cad(b1, v2);
      a[base + 3*s]   = csb(b1, v2);
    }
  }
  __syncthreads();
}

// first DIF radix-4 stage for 8192 with upper half known-zero (skips pad reads/writes)
__device__ void dif8192_pad_stage(cf* __restrict__ a, float sign){
  __syncthreads();
  #pragma unroll
  for (int g = 0; g < 8; g++){
    int w = (int)threadIdx.x + g * TPB;     // 0..2047 ; j = w, base = w
    cf A0 = a[w], B0 = a[w + 2048];
    float sp, cp;
    sincospif((float)w * (1.0f / 4096.0f), &sp, &cp);
    cf w1 = cmk(cp, sign * sp);
    cf w2 = cml(w1, w1);
    cf c1 = cml(A0, w1);
    cf d1 = cml(B0, cmk(-sign * w1.y, sign * w1.x));
    a[w]        = cad(A0, B0);
    a[w + 2048] = cml(csb(A0, B0), w2);
    a[w + 4096] = cad(c1, d1);
    a[w + 6144] = cml(csb(c1, d1), w2);
  }
}

__device__ __forceinline__ int brev13(int x){ return (int)(__brev((unsigned)x) >> 19); }

// ---------------- init atomic-max buffers ----------------
__global__ void k_init(unsigned* xmax, unsigned* ymax){
  int i = blockIdx.x * 256 + threadIdx.x;
  if (i < 2048){ xmax[i] = 0u; ymax[i] = 0u; }
}

// ---------------- transpose x (B,L,H)->(B,H,L), fused max|x| over t ----------------
__global__ __launch_bounds__(256) void k_transpose_x(const float* __restrict__ x,
                                                     float* __restrict__ xT,
                                                     unsigned* __restrict__ xmax){
  __shared__ float tile[64][65];
  __shared__ float red[64][4];
  int b = blockIdx.z;
  int t0 = blockIdx.x * 64;
  int h0 = blockIdx.y * 64;
  int hc = threadIdx.x & 63, tg = threadIdx.x >> 6;
  float pmax = 0.0f;
  #pragma unroll
  for (int q = 0; q < 16; q++){
    int tr = tg + q * 4;
    float v = x[((size_t)(b * 4096 + t0 + tr)) * 256 + h0 + hc];
    tile[tr][hc] = v;
    pmax = fmaxf(pmax, fabsf(v));
  }
  red[hc][tg] = pmax;
  __syncthreads();
  if (threadIdx.x < 64){
    float m = fmaxf(fmaxf(red[threadIdx.x][0], red[threadIdx.x][1]),
                    fmaxf(red[threadIdx.x][2], red[threadIdx.x][3]));
    atomicMax(&xmax[b * 256 + h0 + threadIdx.x], __float_as_uint(m));
  }
  #pragma unroll
  for (int q = 0; q < 16; q++){
    int hr = tg + q * 4;
    xT[((size_t)(b * 256 + h0 + hr)) * 4096 + t0 + hc] = tile[hc][hr];
  }
}

// ---------------- transpose W (256x256) ----------------
__global__ __launch_bounds__(256) void k_wtrans(const float* __restrict__ W, float* __restrict__ WT){
  __shared__ float tile[64][65];
  int j0 = blockIdx.x * 64, k0 = blockIdx.y * 64;
  int c = threadIdx.x & 63, rg = threadIdx.x >> 6;
  #pragma unroll
  for (int q = 0; q < 16; q++){
    int r = rg + q * 4;
    tile[r][c] = W[(j0 + r) * 256 + k0 + c];
  }
  __syncthreads();
  #pragma unroll
  for (int q = 0; q < 16; q++){
    int r = rg + q * 4;
    WT[(k0 + r) * 256 + j0 + c] = tile[c][r];
  }
}

// ---------------- Cauchy / generating function: atRoots (H=256, L=4096) ----------------
__global__ __launch_bounds__(256) void k_cauchy(
    const float* __restrict__ Lr, const float* __restrict__ Li,
    const float* __restrict__ Pr, const float* __restrict__ Pi,
    const float* __restrict__ Qr, const float* __restrict__ Qi,
    const float* __restrict__ Br, const float* __restrict__ Bi,
    const float* __restrict__ Cr, const float* __restrict__ Ci,
    const float* __restrict__ stepp, cf* __restrict__ A)
{
  __shared__ cf sLam[64], sB[64], sP[64], sQB[64], sQP[64];
  __shared__ cf sInv[64][16];   // [n][l]
  __shared__ cf sWood[16], sC[16], sG[16];
  int tid = threadIdx.x;
  int l0 = blockIdx.x * 16;
  float stepv = fmaxf(stepp[0], 1e-6f);
  if (tid < 64){
    cf lam = cmk(Lr[tid], Li[tid]);
    cf b = cmk(Br[tid], Bi[tid]);
    cf p = cmk(Pr[tid], Pi[tid]);
    cf q = cmk(Qr[tid], Qi[tid]);
    sLam[tid] = lam; sB[tid] = b; sP[tid] = p;
    sQB[tid] = cml(q, b);
    sQP[tid] = cml(q, p);
  }
  __syncthreads();
  if (tid < 16){
    int l = l0 + tid;
    float ang = -6.2831855f * ((float)l * (1.0f / 4096.0f));
    cf Om = cmk(cosf(ang), sinf(ang));
    cf den = cmk(1.0f + Om.x, Om.y);
    cf num = cmk(1.0f - Om.x, -Om.y);
    cf rden = crcp(den);
    sC[tid] = cml(cmk(2.0f, 0.0f), rden);
    cf g = cml(num, rden);
    float sc = 2.0f / stepv;
    sG[tid] = cmk(g.x * sc, g.y * sc);
  }
  __syncthreads();
  for (int it = tid; it < 1024; it += 256){
    int n = it >> 4, ll = it & 15;
    sInv[n][ll] = crcp(csb(sG[ll], sLam[n]));
  }
  __syncthreads();
  if (tid < 16){
    cf k10 = cmk(0,0), k11 = cmk(0,0);
    for (int n = 0; n < 64; n++){
      k10 = cad(k10, cml(sQB[n], sInv[n][tid]));
      k11 = cad(k11, cml(sQP[n], sInv[n][tid]));
    }
    sWood[tid] = cdv(k10, cmk(1.0f + k11.x, k11.y));
  }
  __syncthreads();
  int h = tid;
  cf a0[16], a1[16];
  #pragma unroll
  for (int ll = 0; ll < 16; ll++){ a0[ll] = cmk(0,0); a1[ll] = cmk(0,0); }
  for (int n = 0; n < 64; n++){
    cf cc = cmk(Cr[h * 64 + n], Ci[h * 64 + n]);
    cf cb = cml(cc, sB[n]);
    cf cp = cml(cc, sP[n]);
    #pragma unroll
    for (int ll = 0; ll < 16; ll++){
      cf iv = sInv[n][ll];
      a0[ll] = cad(a0[ll], cml(cb, iv));
      a1[ll] = cad(a1[ll], cml(cp, iv));
    }
  }
  cf* dst = A + (size_t)h * 4096 + l0;
  #pragma unroll
  for (int ll = 0; ll < 16; ll++){
    dst[ll] = cml(sC[ll], csb(a0[ll], cml(a1[ll], sWood[ll])));
  }
}

// ---------------- Kf pair tables: per channel pair, Sa/Sb at even bitrev positions ----------------
// Sab record t (t=0..4095): {Sa[p], Sb[p]} at storage position p=2t (natural bin k=brev13(p)),
// scaled by 1/8192. Record 4096: self-pair position p=1 (k=4096). Sa/Sb at partner = conj.
__global__ __launch_bounds__(256) void k_kf(const cf* __restrict__ A, float4* __restrict__ Sab){
  extern __shared__ cf c[];
  int hp = blockIdx.x, tid = threadIdx.x;
  const cf* a1p = A + (size_t)(2 * hp) * 4096;
  const cf* a2p = a1p + 4096;
  for (int l = tid; l < 4096; l += TPB){
    int r = (int)(__brev((unsigned)l) >> 20);   // 12-bit reverse
    cf u = a1p[l], v = a2p[l];
    c[r] = cmk(u.x - v.y, u.y + v.x);           // A1 + i*A2
  }
  fft_dit_r4<4096>(c, 1.0f);                    // unscaled ifft -> k1 + i*k2 (both ~real)
  float k1[16], k2[16];
  #pragma unroll
  for (int q = 0; q < 16; q++){
    cf w = c[tid + q * 256];
    k1[q] = w.x * (1.0f / 4096.0f);
    k2[q] = w.y * (1.0f / 4096.0f);
  }
  __syncthreads();
  #pragma unroll
  for (int q = 0; q < 16; q++) c[tid + q * 256] = cmk(k1[q], k2[q]);  // upper half implicit zero
  dif8192_pad_stage(c, -1.0f);
  fft_dif_r4<8192, 512>(c, -1.0f);              // Z = K1f + i*K2f, bitrev order
  float4* rec = Sab + (size_t)hp * 4097;
  const float sc = 0.5f * 0.5f * (1.0f / 8192.0f);   // the two /2 unpack factors + irfft scale
  #pragma unroll
  for (int q8 = 0; q8 < 16; q8++){
    int t = tid + 256 * q8;
    int p = t << 1;
    int k = brev13(p);
    int qq = brev13((8192 - k) & 8191);
    cf Zp = c[p], Zq = c[qq];
    // K1 = (Zp + conj(Zq))/2 ; K2 = -i*(Zp - conj(Zq))/2  (at natural bin k)
    float K1x = (Zp.x + Zq.x), K1y = (Zp.y - Zq.y);
    float dx  = (Zp.x - Zq.x), dy  = (Zp.y + Zq.y);
    float K2x = dy, K2y = -dx;
    rec[t] = make_float4((K1x + K2x) * sc, (K1y + K2y) * sc,
                         (K1x - K2x) * sc, (K1y - K2y) * sc);
  }
  if (tid == 0){
    cf Z1 = c[1];            // k = 4096, self-paired: K1 = Re(Z1), K2 = Im(Z1) (real)
    float K1x = 2.0f * Z1.x, K2x = 2.0f * Z1.y;
    rec[4096] = make_float4((K1x + K2x) * sc, 0.0f, (K1x - K2x) * sc, 0.0f);
  }
}

// ---------------- conv: 2 channels packed per block ----------------
__global__ __launch_bounds__(256) void k_conv(const float* __restrict__ xT,
                                              const float4* __restrict__ Sab,
                                              const float* __restrict__ Dp,
                                              float* __restrict__ y1T){
  extern __shared__ cf c[];
  int blk = blockIdx.x;             // 0..1023
  int b = blk >> 7, hp = blk & 127;
  int tid = threadIdx.x;
  const float* xs1 = xT + ((size_t)(b * 256 + 2 * hp)) * 4096;
  const float* xs2 = xs1 + 4096;
  for (int t = tid; t < 4096; t += TPB) c[t] = cmk(xs1[t], xs2[t]);
  dif8192_pad_stage(c, -1.0f);
  fft_dif_r4<8192, 512>(c, -1.0f);   // Z bitrev
  const float4* rec = Sab + (size_t)hp * 4097;
  #pragma unroll
  for (int q8 = 0; q8 < 16; q8++){
    int t = tid + 256 * q8;
    int p = t << 1;
    int k = brev13(p);
    int qq = brev13((8192 - k) & 8191);
    cf Zp = c[p], Zq = c[qq];
    float4 r0 = rec[t];
    cf Sap = cmk(r0.x, r0.y), Sbp = cmk(r0.z, r0.w);
    // W[p] = Zp*Sa + conj(Zq)*Sb ;  W[q] = Zq*conj(Sa) + conj(Zp)*conj(Sb)
    cf cZq = cmk(Zq.x, -Zq.y), cZp = cmk(Zp.x, -Zp.y);
    c[p]  = cad(cml(Zp, Sap), cml(cZq, Sbp));
    cf cSa = cmk(Sap.x, -Sap.y), cSb = cmk(Sbp.x, -Sbp.y);
    c[qq] = cad(cml(Zq, cSa), cml(cZp, cSb));
  }
  if (tid == 0){
    float4 e = rec[4096];
    cf Z1 = c[1];
    c[1] = cad(cml(Z1, cmk(e.x, e.y)), cml(cmk(Z1.x, -Z1.y), cmk(e.z, e.w)));
  }
  fft_dit_r4<8192>(c, 1.0f);         // y1 + i*y2 (scale folded into Sab)
  float Dv = Dp[0];
  float* y1 = y1T + ((size_t)(b * 256 + 2 * hp)) * 4096;
  float* y2 = y1 + 4096;
  for (int t = tid; t < 4096; t += TPB){
    cf w = c[t];
    y1[t] = geluf(fmaf(Dv, xs1[t], w.x));
    y2[t] = geluf(fmaf(Dv, xs2[t], w.y));
  }
}

// ---------------- GEMM (y1 @ W^T + b) + gelu + skip + LayerNorm + max|y| ----------------
__global__ __launch_bounds__(256) void k_gemm_ln(
    const float* __restrict__ y1T, const float* __restrict__ WT,
    const float* __restrict__ bfc, const float* __restrict__ x,
    const float* __restrict__ lng, const float* __restrict__ lnb,
    float* __restrict__ yout, unsigned* __restrict__ ymax)
{
  __shared__ float ytile[32][64];
  __shared__ float wtile[32][256];
  __shared__ float red[256][4];
  int tid = threadIdx.x;
  int b  = blockIdx.x >> 6;
  int t0 = (blockIdx.x & 63) << 6;
  int jg = tid & 63;
  int tg = tid >> 6;
  float acc[4][16];
  #pragma unroll
  for (int jj = 0; jj < 4; jj++)
    #pragma unroll
    for (int ti = 0; ti < 16; ti++) acc[jj][ti] = 0.0f;

  int kk = tid >> 3, seg = tid & 7;
  for (int kc = 0; kc < 256; kc += 32){
    __syncthreads();
    const float* ysrc = y1T + ((size_t)(b * 256 + kc + kk)) * 4096 + t0 + seg * 8;
    float4 ya = *(const float4*)(ysrc);
    float4 yb = *(const float4*)(ysrc + 4);
    *(float4*)&ytile[kk][seg * 8]     = ya;
    *(float4*)&ytile[kk][seg * 8 + 4] = yb;
    const float* wsrc = WT + (size_t)(kc + kk) * 256 + seg * 32;
    #pragma unroll
    for (int q = 0; q < 8; q++)
      *(float4*)&wtile[kk][seg * 32 + q * 4] = *(const float4*)(wsrc + q * 4);
    __syncthreads();
    #pragma unroll 4
    for (int k2 = 0; k2 < 32; k2++){
      float4 wv  = *(const float4*)&wtile[k2][jg * 4];
      float4 q0  = *(const float4*)&ytile[k2][tg * 16];
      float4 q1  = *(const float4*)&ytile[k2][tg * 16 + 4];
      float4 q2  = *(const float4*)&ytile[k2][tg * 16 + 8];
      float4 q3  = *(const float4*)&ytile[k2][tg * 16 + 12];
      float yv[16];
      *(float4*)&yv[0]  = q0; *(float4*)&yv[4]  = q1;
      *(float4*)&yv[8]  = q2; *(float4*)&yv[12] = q3;
      float wa[4] = {wv.x, wv.y, wv.z, wv.w};
      #pragma unroll
      for (int jj = 0; jj < 4; jj++)
        #pragma unroll
        for (int ti = 0; ti < 16; ti++)
          acc[jj][ti] = fmaf(wa[jj], yv[ti], acc[jj][ti]);
    }
  }

  float4 bv = *(const float4*)&bfc[jg * 4];
  float4 gv = *(const float4*)&lng[jg * 4];
  float4 lv = *(const float4*)&lnb[jg * 4];
  float ba[4] = {bv.x, bv.y, bv.z, bv.w};
  float ga[4] = {gv.x, gv.y, gv.z, gv.w};
  float la[4] = {lv.x, lv.y, lv.z, lv.w};

  float psum[16], psq[16];
  #pragma unroll
  for (int ti = 0; ti < 16; ti++){ psum[ti] = 0.0f; psq[ti] = 0.0f; }
  #pragma unroll
  for (int ti = 0; ti < 16; ti++){
    int t = t0 + tg * 16 + ti;
    float4 xv = *(const float4*)&x[((size_t)(b * 4096 + t)) * 256 + jg * 4];
    float xa[4] = {xv.x, xv.y, xv.z, xv.w};
    #pragma unroll
    for (int jj = 0; jj < 4; jj++){
      float zz = geluf(acc[jj][ti] + ba[jj]) + xa[jj];
      acc[jj][ti] = zz;
      psum[ti] += zz;
      psq[ti] = fmaf(zz, zz, psq[ti]);
    }
  }
  #pragma unroll
  for (int m = 1; m < 64; m <<= 1){
    #pragma unroll
    for (int ti = 0; ti < 16; ti++){
      psum[ti] += __shfl_xor(psum[ti], m);
      psq[ti]  += __shfl_xor(psq[ti], m);
    }
  }
  float ymx[4] = {0.0f, 0.0f, 0.0f, 0.0f};
  #pragma unroll
  for (int ti = 0; ti < 16; ti++){
    float mu  = psum[ti] * (1.0f / 256.0f);
    float var = psq[ti] * (1.0f / 256.0f) - mu * mu;
    float rstd = rsqrtf(var + 1e-5f);
    int t = t0 + tg * 16 + ti;
    float4 o;
    float oa[4];
    #pragma unroll
    for (int jj = 0; jj < 4; jj++){
      float yv2 = (acc[jj][ti] - mu) * rstd * ga[jj] + la[jj];
      oa[jj] = yv2;
      ymx[jj] = fmaxf(ymx[jj], fabsf(yv2));
    }
    o.x = oa[0]; o.y = oa[1]; o.z = oa[2]; o.w = oa[3];
    *(float4*)&yout[((size_t)(b * 4096 + t)) * 256 + jg * 4] = o;
  }
  __syncthreads();
  #pragma unroll
  for (int jj = 0; jj < 4; jj++) red[jg * 4 + jj][tg] = ymx[jj];
  __syncthreads();
  {
    float m = fmaxf(fmaxf(red[tid][0], red[tid][1]), fmaxf(red[tid][2], red[tid][3]));
    atomicMax(&ymax[b * 256 + tid], __float_as_uint(m));
  }
}

// ---------------- final ratio ----------------
__global__ void k_ratio(const unsigned* __restrict__ ymax, const unsigned* __restrict__ xmax,
                        float* __restrict__ out){
  int i = blockIdx.x * 256 + threadIdx.x;
  if (i < 2048){
    float ym = __uint_as_float(ymax[i]);
    float xm = __uint_as_float(xmax[i]);
    out[8388608 + i] = ym / (xm + 1e-6f);
  }
}

extern "C" void kernel_launch(void* const* d_in, const int* in_sizes, int n_in,
                              void* d_out, int out_size, void* d_ws, size_t ws_size,
                              hipStream_t stream)
{
  const float* x    = (const float*)d_in[0];
  const float* Lr   = (const float*)d_in[1];
  const float* Li   = (const float*)d_in[2];
  const float* Pr   = (const float*)d_in[3];
  const float* Pi   = (const float*)d_in[4];
  const float* Qr   = (const float*)d_in[5];
  const float* Qi   = (const float*)d_in[6];
  const float* Br   = (const float*)d_in[7];
  const float* Bi   = (const float*)d_in[8];
  const float* Cr   = (const float*)d_in[9];
  const float* Ci   = (const float*)d_in[10];
  const float* stp  = (const float*)d_in[11];
  const float* Dp   = (const float*)d_in[12];
  const float* Wfc  = (const float*)d_in[13];
  const float* bfc  = (const float*)d_in[14];
  const float* lng  = (const float*)d_in[15];
  const float* lnb  = (const float*)d_in[16];

  char* ws = (char*)d_ws;
  float*    xT   = (float*)(ws);                                   // 32 MB
  float4*   Sab  = (float4*)(ws + ((size_t)32 << 20));             // ~8 MB (128 x 4097 x 16B)
  float*    y1T  = (float*)(ws + ((size_t)41 << 20));              // 32 MB
  cf*       A    = (cf*)(ws + ((size_t)41 << 20));                 // 8 MB overlay (dead before y1T written)
  float*    WT   = (float*)(ws + ((size_t)73 << 20));              // 256 KB
  unsigned* xmax = (unsigned*)(ws + ((size_t)73 << 20) + (256u << 10));
  unsigned* ymax = xmax + 2048;

  k_init<<<8, 256, 0, stream>>>(xmax, ymax);
  dim3 gt(64, 4, 8);
  k_transpose_x<<<gt, 256, 0, stream>>>(x, xT, xmax);
  k_wtrans<<<dim3(4, 4), 256, 0, stream>>>(Wfc, WT);
  k_cauchy<<<256, 256, 0, stream>>>(Lr, Li, Pr, Pi, Qr, Qi, Br, Bi, Cr, Ci, stp, A);
  k_kf<<<128, 256, 65536, stream>>>(A, Sab);
  k_conv<<<1024, 256, 65536, stream>>>(xT, Sab, Dp, y1T);
  k_gemm_ln<<<512, 256, 0, stream>>>(y1T, WT, bfc, x, lng, lnb, (float*)d_out, ymax);
  k_ratio<<<8, 256, 0, stream>>>(ymax, xmax, (float*)d_out);
}

// Round 3
// 215.367 us; speedup vs baseline: 2.9366x; 1.2788x over previous
//
#include <hip/hip_runtime.h>
#include <math.h>

#define TPB 256

typedef float2 cf;
typedef __attribute__((ext_vector_type(8))) short bf16x8;
typedef __attribute__((ext_vector_type(4))) float f32x4;

__device__ __forceinline__ cf cmk(float x, float y){ cf r; r.x=x; r.y=y; return r; }
__device__ __forceinline__ cf cml(cf a, cf b){ return cmk(a.x*b.x - a.y*b.y, a.x*b.y + a.y*b.x); }
__device__ __forceinline__ cf cad(cf a, cf b){ return cmk(a.x+b.x, a.y+b.y); }
__device__ __forceinline__ cf csb(cf a, cf b){ return cmk(a.x-b.x, a.y-b.y); }
__device__ __forceinline__ cf crcp(cf d){ float r = 1.0f/(d.x*d.x + d.y*d.y); return cmk(d.x*r, -d.y*r); }
__device__ __forceinline__ cf cdv(cf n, cf d){ return cml(n, crcp(d)); }
__device__ __forceinline__ float geluf(float z){ return 0.5f*z*(1.0f + erff(z*0.70710678118654752f)); }

// exp(sign*i*pi*f) via native v_sin/v_cos (input in revolutions: sin(2*pi*x))
__device__ __forceinline__ cf twid(float f, float sign){
  float h = f * 0.5f;
  float s = __builtin_amdgcn_sinf(h);
  float c0 = __builtin_amdgcn_cosf(h);
  return cmk(c0, sign * s);
}

// round-to-nearest-even bf16 split: v ~= hi + lo
__device__ __forceinline__ void bfsplit(float v, ushort* h, ushort* l){
  unsigned u = __float_as_uint(v);
  unsigned hr = (u + 0x7FFFu + ((u >> 16) & 1u)) & 0xFFFF0000u;
  *h = (ushort)(hr >> 16);
  float lv = v - __uint_as_float(hr);
  unsigned u2 = __float_as_uint(lv);
  *l = (ushort)((u2 + 0x7FFFu + ((u2 >> 16) & 1u)) >> 16);
}

// ---------------- radix-4 FFT primitives (in-place, LDS, 256 threads) ----------------
template<int N, int SSTART>
__device__ void fft_dif_r4(cf* __restrict__ a, float sign){
  #pragma unroll
  for (int s = SSTART; s >= 1; s >>= 2){
    __syncthreads();
    #pragma unroll
    for (int g = 0; g < (N >> 2) / TPB; g++){
      int w = (int)threadIdx.x + g * TPB;
      int j = w & (s - 1);
      int base = ((w & ~(s - 1)) << 2) | j;
      cf A0 = a[base], B0 = a[base + s], C0 = a[base + 2*s], D0 = a[base + 3*s];
      cf w1 = twid((float)j / (float)(2 * s), sign);
      cf w2 = cml(w1, w1);
      cf a1 = cad(A0, C0);
      cf c1 = cml(csb(A0, C0), w1);
      cf b1 = cad(B0, D0);
      cf d1 = cml(csb(B0, D0), cmk(-sign * w1.y, sign * w1.x));
      a[base]         = cad(a1, b1);
      a[base + s]     = cml(csb(a1, b1), w2);
      a[base + 2*s]   = cad(c1, d1);
      a[base + 3*s]   = cml(csb(c1, d1), w2);
    }
  }
  if constexpr ((__builtin_ctz(N) & 1) == 1){
    __syncthreads();
    #pragma unroll
    for (int g = 0; g < (N >> 1) / TPB; g++){
      int w = (int)threadIdx.x + g * TPB;
      int i = w << 1;
      cf u = a[i], v = a[i + 1];
      a[i] = cad(u, v);
      a[i + 1] = csb(u, v);
    }
  }
  __syncthreads();
}

template<int N>
__device__ void fft_dit_r4(cf* __restrict__ a, float sign){
  if constexpr ((__builtin_ctz(N) & 1) == 1){
    __syncthreads();
    #pragma unroll
    for (int g = 0; g < (N >> 1) / TPB; g++){
      int w = (int)threadIdx.x + g * TPB;
      int i = w << 1;
      cf u = a[i], v = a[i + 1];
      a[i] = cad(u, v);
      a[i + 1] = csb(u, v);
    }
  }
  constexpr int S0 = ((__builtin_ctz(N) & 1) == 1) ? 2 : 1;
  #pragma unroll
  for (int s = S0; s <= (N >> 2); s <<= 2){
    __syncthreads();
    #pragma unroll
    for (int g = 0; g < (N >> 2) / TPB; g++){
      int w = (int)threadIdx.x + g * TPB;
      int j = w & (s - 1);
      int base = ((w & ~(s - 1)) << 2) | j;
      cf A0 = a[base], B0 = a[base + s], C0 = a[base + 2*s], D0 = a[base + 3*s];
      cf w1 = twid((float)j / (float)(2 * s), sign);
      cf w2 = cml(w1, w1);
      cf t1 = cml(B0, w2);
      cf a1 = cad(A0, t1), b1 = csb(A0, t1);
      cf t2 = cml(D0, w2);
      cf c1 = cad(C0, t2), d1 = csb(C0, t2);
      cf v1 = cml(c1, w1);
      cf v2 = cml(d1, cmk(-sign * w1.y, sign * w1.x));
      a[base]         = cad(a1, v1);
      a[base + 2*s]   = csb(a1, v1);
      a[base + s]     = cad(b1, v2);
      a[base + 3*s]   = csb(b1, v2);
    }
  }
  __syncthreads();
}

// first DIF radix-4 stage for 8192 with upper half known-zero
__device__ void dif8192_pad_stage(cf* __restrict__ a, float sign){
  __syncthreads();
  #pragma unroll
  for (int g = 0; g < 8; g++){
    int w = (int)threadIdx.x + g * TPB;
    cf A0 = a[w], B0 = a[w + 2048];
    cf w1 = twid((float)w * (1.0f / 4096.0f), sign);
    cf w2 = cml(w1, w1);
    cf c1 = cml(A0, w1);
    cf d1 = cml(B0, cmk(-sign * w1.y, sign * w1.x));
    a[w]        = cad(A0, B0);
    a[w + 2048] = cml(csb(A0, B0), w2);
    a[w + 4096] = cad(c1, d1);
    a[w + 6144] = cml(csb(c1, d1), w2);
  }
}

__device__ __forceinline__ int brev13(int x){ return (int)(__brev((unsigned)x) >> 19); }

// ---------------- init atomic-max buffers ----------------
__global__ void k_init(unsigned* xmax, unsigned* ymax){
  int i = blockIdx.x * 256 + threadIdx.x;
  if (i < 2048){ xmax[i] = 0u; ymax[i] = 0u; }
}

// ---------------- transpose x (B,L,H)->(B,H,L), fused max|x| ----------------
__global__ __launch_bounds__(256) void k_transpose_x(const float* __restrict__ x,
                                                     float* __restrict__ xT,
                                                     unsigned* __restrict__ xmax){
  __shared__ float tile[64][65];
  __shared__ float red[64][4];
  int b = blockIdx.z;
  int t0 = blockIdx.x * 64;
  int h0 = blockIdx.y * 64;
  int hc = threadIdx.x & 63, tg = threadIdx.x >> 6;
  float pmax = 0.0f;
  #pragma unroll
  for (int q = 0; q < 16; q++){
    int tr = tg + q * 4;
    float v = x[((size_t)(b * 4096 + t0 + tr)) * 256 + h0 + hc];
    tile[tr][hc] = v;
    pmax = fmaxf(pmax, fabsf(v));
  }
  red[hc][tg] = pmax;
  __syncthreads();
  if (threadIdx.x < 64){
    float m = fmaxf(fmaxf(red[threadIdx.x][0], red[threadIdx.x][1]),
                    fmaxf(red[threadIdx.x][2], red[threadIdx.x][3]));
    atomicMax(&xmax[b * 256 + h0 + threadIdx.x], __float_as_uint(m));
  }
  #pragma unroll
  for (int q = 0; q < 16; q++){
    int hr = tg + q * 4;
    xT[((size_t)(b * 256 + h0 + hr)) * 4096 + t0 + hc] = tile[hc][hr];
  }
}

// ---------------- W -> bf16 hi/lo planes (layout kept (j,k)) ----------------
__global__ void k_wsplit(const float* __restrict__ W, ushort* __restrict__ Wh, ushort* __restrict__ Wl){
  int i = blockIdx.x * 256 + threadIdx.x;   // 65536
  ushort h, l;
  bfsplit(W[i], &h, &l);
  Wh[i] = h; Wl[i] = l;
}

// ---------------- Cauchy / generating function ----------------
__global__ __launch_bounds__(256) void k_cauchy(
    const float* __restrict__ Lr, const float* __restrict__ Li,
    const float* __restrict__ Pr, const float* __restrict__ Pi,
    const float* __restrict__ Qr, const float* __restrict__ Qi,
    const float* __restrict__ Br, const float* __restrict__ Bi,
    const float* __restrict__ Cr, const float* __restrict__ Ci,
    const float* __restrict__ stepp, cf* __restrict__ A)
{
  __shared__ cf sLam[64], sB[64], sP[64], sQB[64], sQP[64];
  __shared__ cf sInv[64][16];
  __shared__ cf sWood[16], sC[16], sG[16];
  int tid = threadIdx.x;
  int l0 = blockIdx.x * 16;
  float stepv = fmaxf(stepp[0], 1e-6f);
  if (tid < 64){
    cf lam = cmk(Lr[tid], Li[tid]);
    cf b = cmk(Br[tid], Bi[tid]);
    cf p = cmk(Pr[tid], Pi[tid]);
    cf q = cmk(Qr[tid], Qi[tid]);
    sLam[tid] = lam; sB[tid] = b; sP[tid] = p;
    sQB[tid] = cml(q, b);
    sQP[tid] = cml(q, p);
  }
  __syncthreads();
  if (tid < 16){
    int l = l0 + tid;
    float ang = -6.2831855f * ((float)l * (1.0f / 4096.0f));
    cf Om = cmk(cosf(ang), sinf(ang));
    cf den = cmk(1.0f + Om.x, Om.y);
    cf num = cmk(1.0f - Om.x, -Om.y);
    cf rden = crcp(den);
    sC[tid] = cml(cmk(2.0f, 0.0f), rden);
    cf g = cml(num, rden);
    float sc = 2.0f / stepv;
    sG[tid] = cmk(g.x * sc, g.y * sc);
  }
  __syncthreads();
  for (int it = tid; it < 1024; it += 256){
    int n = it >> 4, ll = it & 15;
    sInv[n][ll] = crcp(csb(sG[ll], sLam[n]));
  }
  __syncthreads();
  if (tid < 16){
    cf k10 = cmk(0,0), k11 = cmk(0,0);
    for (int n = 0; n < 64; n++){
      k10 = cad(k10, cml(sQB[n], sInv[n][tid]));
      k11 = cad(k11, cml(sQP[n], sInv[n][tid]));
    }
    sWood[tid] = cdv(k10, cmk(1.0f + k11.x, k11.y));
  }
  __syncthreads();
  int h = tid;
  cf a0[16], a1[16];
  #pragma unroll
  for (int ll = 0; ll < 16; ll++){ a0[ll] = cmk(0,0); a1[ll] = cmk(0,0); }
  for (int n = 0; n < 64; n++){
    cf cc = cmk(Cr[h * 64 + n], Ci[h * 64 + n]);
    cf cb = cml(cc, sB[n]);
    cf cp = cml(cc, sP[n]);
    #pragma unroll
    for (int ll = 0; ll < 16; ll++){
      cf iv = sInv[n][ll];
      a0[ll] = cad(a0[ll], cml(cb, iv));
      a1[ll] = cad(a1[ll], cml(cp, iv));
    }
  }
  cf* dst = A + (size_t)h * 4096 + l0;
  #pragma unroll
  for (int ll = 0; ll < 16; ll++){
    dst[ll] = cml(sC[ll], csb(a0[ll], cml(a1[ll], sWood[ll])));
  }
}

// ---------------- Kf pair tables ----------------
__global__ __launch_bounds__(256) void k_kf(const cf* __restrict__ A, float4* __restrict__ Sab){
  extern __shared__ cf c[];
  int hp = blockIdx.x, tid = threadIdx.x;
  const cf* a1p = A + (size_t)(2 * hp) * 4096;
  const cf* a2p = a1p + 4096;
  for (int l = tid; l < 4096; l += TPB){
    int r = (int)(__brev((unsigned)l) >> 20);
    cf u = a1p[l], v = a2p[l];
    c[r] = cmk(u.x - v.y, u.y + v.x);
  }
  fft_dit_r4<4096>(c, 1.0f);
  float k1[16], k2[16];
  #pragma unroll
  for (int q = 0; q < 16; q++){
    cf w = c[tid + q * 256];
    k1[q] = w.x * (1.0f / 4096.0f);
    k2[q] = w.y * (1.0f / 4096.0f);
  }
  __syncthreads();
  #pragma unroll
  for (int q = 0; q < 16; q++) c[tid + q * 256] = cmk(k1[q], k2[q]);
  dif8192_pad_stage(c, -1.0f);
  fft_dif_r4<8192, 512>(c, -1.0f);
  float4* rec = Sab + (size_t)hp * 4097;
  const float sc = 0.5f * 0.5f * (1.0f / 8192.0f);
  #pragma unroll
  for (int q8 = 0; q8 < 16; q8++){
    int t = tid + 256 * q8;
    int p = t << 1;
    int k = brev13(p);
    int qq = brev13((8192 - k) & 8191);
    cf Zp = c[p], Zq = c[qq];
    float K1x = (Zp.x + Zq.x), K1y = (Zp.y - Zq.y);
    float dx  = (Zp.x - Zq.x), dy  = (Zp.y + Zq.y);
    float K2x = dy, K2y = -dx;
    rec[t] = make_float4((K1x + K2x) * sc, (K1y + K2y) * sc,
                         (K1x - K2x) * sc, (K1y - K2y) * sc);
  }
  if (tid == 0){
    cf Z1 = c[1];
    float K1x = 2.0f * Z1.x, K2x = 2.0f * Z1.y;
    rec[4096] = make_float4((K1x + K2x) * sc, 0.0f, (K1x - K2x) * sc, 0.0f);
  }
}

// ---------------- conv: 2 channels packed per block; emits bf16 hi/lo planes ----------------
__global__ __launch_bounds__(256) void k_conv(const float* __restrict__ xT,
                                              const float4* __restrict__ Sab,
                                              const float* __restrict__ Dp,
                                              ushort* __restrict__ y1h,
                                              ushort* __restrict__ y1l){
  extern __shared__ cf c[];
  int blk = blockIdx.x;
  int b = blk >> 7, hp = blk & 127;
  int tid = threadIdx.x;
  const float* xs1 = xT + ((size_t)(b * 256 + 2 * hp)) * 4096;
  const float* xs2 = xs1 + 4096;
  for (int t = tid; t < 4096; t += TPB) c[t] = cmk(xs1[t], xs2[t]);
  dif8192_pad_stage(c, -1.0f);
  fft_dif_r4<8192, 512>(c, -1.0f);
  const float4* rec = Sab + (size_t)hp * 4097;
  #pragma unroll
  for (int q8 = 0; q8 < 16; q8++){
    int t = tid + 256 * q8;
    int p = t << 1;
    int k = brev13(p);
    int qq = brev13((8192 - k) & 8191);
    cf Zp = c[p], Zq = c[qq];
    float4 r0 = rec[t];
    cf Sap = cmk(r0.x, r0.y), Sbp = cmk(r0.z, r0.w);
    cf cZq = cmk(Zq.x, -Zq.y), cZp = cmk(Zp.x, -Zp.y);
    c[p]  = cad(cml(Zp, Sap), cml(cZq, Sbp));
    cf cSa = cmk(Sap.x, -Sap.y), cSb = cmk(Sbp.x, -Sbp.y);
    c[qq] = cad(cml(Zq, cSa), cml(cZp, cSb));
  }
  if (tid == 0){
    float4 e = rec[4096];
    cf Z1 = c[1];
    c[1] = cad(cml(Z1, cmk(e.x, e.y)), cml(cmk(Z1.x, -Z1.y), cmk(e.z, e.w)));
  }
  fft_dit_r4<8192>(c, 1.0f);
  float Dv = Dp[0];
  size_t base = ((size_t)(b * 256 + 2 * hp)) * 4096;
  for (int t = tid; t < 4096; t += TPB){
    cf w = c[t];
    float z1 = geluf(fmaf(Dv, xs1[t], w.x));
    float z2 = geluf(fmaf(Dv, xs2[t], w.y));
    ushort h0, l0, h1, l1;
    bfsplit(z1, &h0, &l0);
    bfsplit(z2, &h1, &l1);
    y1h[base + t] = h0;        y1l[base + t] = l0;
    y1h[base + 4096 + t] = h1; y1l[base + 4096 + t] = l1;
  }
}

// ---------------- MFMA split-bf16 GEMM + gelu + skip + LayerNorm + max|y| ----------------
// OUT[t][j] = sum_k Y[t][k] * W[j][k] ; A-frag: Y[l&15][(l>>4)*8+i], B-frag: W[(l>>4)*8+i ... k][l&15 -> j]
__global__ __launch_bounds__(256, 3) void k_gemm_ln(
    const ushort* __restrict__ y1h, const ushort* __restrict__ y1l,
    const ushort* __restrict__ Wh, const ushort* __restrict__ Wl,
    const float* __restrict__ bfc, const float* __restrict__ x,
    const float* __restrict__ lng, const float* __restrict__ lnb,
    float* __restrict__ yout, unsigned* __restrict__ ymax)
{
  __shared__ ushort sY[2][64 * 40];       // [plane][t][k-swizzled], pitch 40
  __shared__ float red1[64][4], red2[64][4];
  int tid = threadIdx.x;
  int l = tid & 63;
  int w = tid >> 6;                       // wave -> j quadrant
  int blk = blockIdx.x;                   // 512
  int b = blk >> 6;
  int t0 = (blk & 63) * 64;
  int g = l >> 4, cc = l & 15;

  f32x4 acc[4][4];
  #pragma unroll
  for (int m = 0; m < 4; m++)
    #pragma unroll
    for (int n = 0; n < 4; n++)
      acc[m][n] = (f32x4){0.0f, 0.0f, 0.0f, 0.0f};

  int kk = tid >> 3, ts = (tid & 7) * 8;

  #pragma unroll 1
  for (int kc = 0; kc < 256; kc += 32){
    __syncthreads();
    // stage Y tile (32 k x 64 t) transposed to [t][k] with k-block xor swizzle
    {
      size_t gb = ((size_t)(b * 256 + kc + kk)) * 4096 + t0 + ts;
      float4 vh = *(const float4*)(y1h + gb);
      float4 vl = *(const float4*)(y1l + gb);
      const ushort* ph = (const ushort*)&vh;
      const ushort* pl = (const ushort*)&vl;
      int kblk = kk >> 3, kin = kk & 7;
      #pragma unroll
      for (int e = 0; e < 8; e++){
        int t = ts + e;
        int idx = t * 40 + ((kblk ^ ((t >> 3) & 3)) << 3) + kin;
        sY[0][idx] = ph[e];
        sY[1][idx] = pl[e];
      }
    }
    __syncthreads();
    // A-frags from LDS
    bf16x8 afh[4], afl[4];
    #pragma unroll
    for (int m = 0; m < 4; m++){
      int t = m * 16 + cc;
      int idx = t * 40 + ((g ^ ((t >> 3) & 3)) << 3);
      afh[m] = *(bf16x8*)&sY[0][idx];
      afl[m] = *(bf16x8*)&sY[1][idx];
    }
    // B-frags straight from global (L2-resident W), 3-term split MFMA
    #pragma unroll
    for (int n = 0; n < 4; n++){
      size_t wj = (size_t)(w * 64 + n * 16 + cc) * 256 + kc + g * 8;
      bf16x8 bh = *(const bf16x8*)(Wh + wj);
      bf16x8 bl = *(const bf16x8*)(Wl + wj);
      #pragma unroll
      for (int m = 0; m < 4; m++){
        acc[m][n] = __builtin_amdgcn_mfma_f32_16x16x32_bf16(afh[m], bh, acc[m][n], 0, 0, 0);
        acc[m][n] = __builtin_amdgcn_mfma_f32_16x16x32_bf16(afh[m], bl, acc[m][n], 0, 0, 0);
        acc[m][n] = __builtin_amdgcn_mfma_f32_16x16x32_bf16(afl[m], bh, acc[m][n], 0, 0, 0);
      }
    }
  }

  // ---- epilogue: z = gelu(acc + bias) + x ; LayerNorm over j ; max|y| ----
  float bj[4], gj[4], lj[4];
  #pragma unroll
  for (int n = 0; n < 4; n++){
    int j = w * 64 + n * 16 + cc;
    bj[n] = bfc[j]; gj[n] = lng[j]; lj[n] = lnb[j];
  }
  #pragma unroll
  for (int m = 0; m < 4; m++){
    #pragma unroll
    for (int r = 0; r < 4; r++){
      int tl = m * 16 + g * 4 + r;
      size_t rowb = ((size_t)(b * 4096 + t0 + tl)) * 256;
      float ss = 0.0f, sq = 0.0f;
      #pragma unroll
      for (int n = 0; n < 4; n++){
        float z = geluf(acc[m][n][r] + bj[n]) + x[rowb + w * 64 + n * 16 + cc];
        acc[m][n][r] = z;
        ss += z; sq = fmaf(z, z, sq);
      }
      #pragma unroll
      for (int msk = 1; msk < 16; msk <<= 1){
        ss += __shfl_xor(ss, msk);
        sq += __shfl_xor(sq, msk);
      }
      if (cc == 0){ red1[tl][w] = ss; red2[tl][w] = sq; }
    }
  }
  __syncthreads();
  float jm[4] = {0.0f, 0.0f, 0.0f, 0.0f};
  #pragma unroll
  for (int m = 0; m < 4; m++){
    #pragma unroll
    for (int r = 0; r < 4; r++){
      int tl = m * 16 + g * 4 + r;
      float ts1 = red1[tl][0] + red1[tl][1] + red1[tl][2] + red1[tl][3];
      float ts2 = red2[tl][0] + red2[tl][1] + red2[tl][2] + red2[tl][3];
      float mu = ts1 * (1.0f / 256.0f);
      float var = ts2 * (1.0f / 256.0f) - mu * mu;
      float rstd = rsqrtf(var + 1e-5f);
      size_t rowb = ((size_t)(b * 4096 + t0 + tl)) * 256;
      #pragma unroll
      for (int n = 0; n < 4; n++){
        float yv = (acc[m][n][r] - mu) * rstd * gj[n] + lj[n];
        yout[rowb + w * 64 + n * 16 + cc] = yv;
        jm[n] = fmaxf(jm[n], fabsf(yv));
      }
    }
  }
  #pragma unroll
  for (int n = 0; n < 4; n++){
    jm[n] = fmaxf(jm[n], __shfl_xor(jm[n], 16));
    jm[n] = fmaxf(jm[n], __shfl_xor(jm[n], 32));
  }
  if (g == 0){
    #pragma unroll
    for (int n = 0; n < 4; n++)
      atomicMax(&ymax[b * 256 + w * 64 + n * 16 + cc], __float_as_uint(jm[n]));
  }
}

// ---------------- final ratio ----------------
__global__ void k_ratio(const unsigned* __restrict__ ymax, const unsigned* __restrict__ xmax,
                        float* __restrict__ out){
  int i = blockIdx.x * 256 + threadIdx.x;
  if (i < 2048){
    float ym = __uint_as_float(ymax[i]);
    float xm = __uint_as_float(xmax[i]);
    out[8388608 + i] = ym / (xm + 1e-6f);
  }
}

extern "C" void kernel_launch(void* const* d_in, const int* in_sizes, int n_in,
                              void* d_out, int out_size, void* d_ws, size_t ws_size,
                              hipStream_t stream)
{
  const float* x    = (const float*)d_in[0];
  const float* Lr   = (const float*)d_in[1];
  const float* Li   = (const float*)d_in[2];
  const float* Pr   = (const float*)d_in[3];
  const float* Pi   = (const float*)d_in[4];
  const float* Qr   = (const float*)d_in[5];
  const float* Qi   = (const float*)d_in[6];
  const float* Br   = (const float*)d_in[7];
  const float* Bi   = (const float*)d_in[8];
  const float* Cr   = (const float*)d_in[9];
  const float* Ci   = (const float*)d_in[10];
  const float* stp  = (const float*)d_in[11];
  const float* Dp   = (const float*)d_in[12];
  const float* Wfc  = (const float*)d_in[13];
  const float* bfc  = (const float*)d_in[14];
  const float* lng  = (const float*)d_in[15];
  const float* lnb  = (const float*)d_in[16];

  char* ws = (char*)d_ws;
  float*    xT   = (float*)(ws);                                   // 32 MB
  float4*   Sab  = (float4*)(ws + ((size_t)32 << 20));             // ~8.4 MB
  cf*       A    = (cf*)(ws + ((size_t)41 << 20));                 // 8 MB (dead after k_kf)
  ushort*   y1h  = (ushort*)(ws + ((size_t)41 << 20));             // 16 MB (overlays A)
  ushort*   y1l  = (ushort*)(ws + ((size_t)57 << 20));             // 16 MB
  ushort*   Wh   = (ushort*)(ws + ((size_t)73 << 20));             // 128 KB
  ushort*   Wl   = (ushort*)(ws + ((size_t)73 << 20) + (128u << 10));
  unsigned* xmax = (unsigned*)(ws + ((size_t)73 << 20) + (256u << 10));
  unsigned* ymax = xmax + 2048;

  k_init<<<8, 256, 0, stream>>>(xmax, ymax);
  dim3 gt(64, 4, 8);
  k_transpose_x<<<gt, 256, 0, stream>>>(x, xT, xmax);
  k_wsplit<<<256, 256, 0, stream>>>(Wfc, Wh, Wl);
  k_cauchy<<<256, 256, 0, stream>>>(Lr, Li, Pr, Pi, Qr, Qi, Br, Bi, Cr, Ci, stp, A);
  k_kf<<<128, 256, 65536, stream>>>(A, Sab);
  k_conv<<<1024, 256, 65536, stream>>>(xT, Sab, Dp, y1h, y1l);
  k_gemm_ln<<<512, 256, 0, stream>>>(y1h, y1l, Wh, Wl, bfc, x, lng, lnb, (float*)d_out, ymax);
  k_ratio<<<8, 256, 0, stream>>>(ymax, xmax, (float*)d_out);
}

// Round 4
// 211.151 us; speedup vs baseline: 2.9952x; 1.0200x over previous
//
#include <hip/hip_runtime.h>
#include <math.h>

#define TPB 256

typedef float2 cf;
typedef __attribute__((ext_vector_type(8))) short bf16x8;
typedef __attribute__((ext_vector_type(4))) float f32x4;

__device__ __forceinline__ cf cmk(float x, float y){ cf r; r.x=x; r.y=y; return r; }
__device__ __forceinline__ cf cml(cf a, cf b){ return cmk(a.x*b.x - a.y*b.y, a.x*b.y + a.y*b.x); }
__device__ __forceinline__ cf cad(cf a, cf b){ return cmk(a.x+b.x, a.y+b.y); }
__device__ __forceinline__ cf csb(cf a, cf b){ return cmk(a.x-b.x, a.y-b.y); }
__device__ __forceinline__ cf crcp(cf d){ float r = 1.0f/(d.x*d.x + d.y*d.y); return cmk(d.x*r, -d.y*r); }
__device__ __forceinline__ cf cdv(cf n, cf d){ return cml(n, crcp(d)); }
__device__ __forceinline__ float geluf(float z){ return 0.5f*z*(1.0f + erff(z*0.70710678118654752f)); }

// exp(sign*i*pi*f) via native v_sin/v_cos (input in revolutions)
__device__ __forceinline__ cf twid(float f, float sign){
  float h = f * 0.5f;
  float s = __builtin_amdgcn_sinf(h);
  float c0 = __builtin_amdgcn_cosf(h);
  return cmk(c0, sign * s);
}

__device__ __forceinline__ cf shflx(cf v, int m){
  return cmk(__shfl_xor(v.x, m), __shfl_xor(v.y, m));
}

// round-to-nearest-even bf16 split: v ~= hi + lo
__device__ __forceinline__ void bfsplit(float v, ushort* h, ushort* l){
  unsigned u = __float_as_uint(v);
  unsigned hr = (u + 0x7FFFu + ((u >> 16) & 1u)) & 0xFFFF0000u;
  *h = (ushort)(hr >> 16);
  float lv = v - __uint_as_float(hr);
  unsigned u2 = __float_as_uint(lv);
  *l = (ushort)((u2 + 0x7FFFu + ((u2 >> 16) & 1u)) >> 16);
}

// radix-4 butterflies on a register quad (q0..q3 at strides 0,s,2s,3s), w1 = W_{4s}^j
__device__ __forceinline__ void dif4q(cf& q0, cf& q1, cf& q2, cf& q3, cf w1, float sign){
  cf w2 = cml(w1, w1);
  cf a1 = cad(q0, q2);
  cf c1 = cml(csb(q0, q2), w1);
  cf b1 = cad(q1, q3);
  cf d1 = cml(csb(q1, q3), cmk(-sign*w1.y, sign*w1.x));
  q0 = cad(a1, b1);
  q1 = cml(csb(a1, b1), w2);
  q2 = cad(c1, d1);
  q3 = cml(csb(c1, d1), w2);
}
__device__ __forceinline__ void dit4q(cf& q0, cf& q1, cf& q2, cf& q3, cf w1, float sign){
  cf w2 = cml(w1, w1);
  cf t1 = cml(q1, w2);
  cf a1 = cad(q0, t1), b1 = csb(q0, t1);
  cf t2 = cml(q3, w2);
  cf c1 = cad(q2, t2), d1 = csb(q2, t2);
  cf v1 = cml(c1, w1);
  cf v2 = cml(d1, cmk(-sign*w1.y, sign*w1.x));
  q0 = cad(a1, v1);
  q2 = csb(a1, v1);
  q1 = cad(b1, v2);
  q3 = csb(b1, v2);
}

// ---------------- legacy LDS FFT primitives (used by k_kf only) ----------------
template<int N, int SSTART>
__device__ void fft_dif_r4(cf* __restrict__ a, float sign){
  #pragma unroll
  for (int s = SSTART; s >= 1; s >>= 2){
    __syncthreads();
    #pragma unroll
    for (int g = 0; g < (N >> 2) / TPB; g++){
      int w = (int)threadIdx.x + g * TPB;
      int j = w & (s - 1);
      int base = ((w & ~(s - 1)) << 2) | j;
      cf A0 = a[base], B0 = a[base + s], C0 = a[base + 2*s], D0 = a[base + 3*s];
      cf w1 = twid((float)j / (float)(2 * s), sign);
      cf w2 = cml(w1, w1);
      cf a1 = cad(A0, C0);
      cf c1 = cml(csb(A0, C0), w1);
      cf b1 = cad(B0, D0);
      cf d1 = cml(csb(B0, D0), cmk(-sign * w1.y, sign * w1.x));
      a[base]         = cad(a1, b1);
      a[base + s]     = cml(csb(a1, b1), w2);
      a[base + 2*s]   = cad(c1, d1);
      a[base + 3*s]   = cml(csb(c1, d1), w2);
    }
  }
  if constexpr ((__builtin_ctz(N) & 1) == 1){
    __syncthreads();
    #pragma unroll
    for (int g = 0; g < (N >> 1) / TPB; g++){
      int w = (int)threadIdx.x + g * TPB;
      int i = w << 1;
      cf u = a[i], v = a[i + 1];
      a[i] = cad(u, v);
      a[i + 1] = csb(u, v);
    }
  }
  __syncthreads();
}

template<int N>
__device__ void fft_dit_r4(cf* __restrict__ a, float sign){
  if constexpr ((__builtin_ctz(N) & 1) == 1){
    __syncthreads();
    #pragma unroll
    for (int g = 0; g < (N >> 1) / TPB; g++){
      int w = (int)threadIdx.x + g * TPB;
      int i = w << 1;
      cf u = a[i], v = a[i + 1];
      a[i] = cad(u, v);
      a[i + 1] = csb(u, v);
    }
  }
  constexpr int S0 = ((__builtin_ctz(N) & 1) == 1) ? 2 : 1;
  #pragma unroll
  for (int s = S0; s <= (N >> 2); s <<= 2){
    __syncthreads();
    #pragma unroll
    for (int g = 0; g < (N >> 2) / TPB; g++){
      int w = (int)threadIdx.x + g * TPB;
      int j = w & (s - 1);
      int base = ((w & ~(s - 1)) << 2) | j;
      cf A0 = a[base], B0 = a[base + s], C0 = a[base + 2*s], D0 = a[base + 3*s];
      cf w1 = twid((float)j / (float)(2 * s), sign);
      cf w2 = cml(w1, w1);
      cf t1 = cml(B0, w2);
      cf a1 = cad(A0, t1), b1 = csb(A0, t1);
      cf t2 = cml(D0, w2);
      cf c1 = cad(C0, t2), d1 = csb(C0, t2);
      cf v1 = cml(c1, w1);
      cf v2 = cml(d1, cmk(-sign * w1.y, sign * w1.x));
      a[base]         = cad(a1, v1);
      a[base + 2*s]   = csb(a1, v1);
      a[base + s]     = cad(b1, v2);
      a[base + 3*s]   = csb(b1, v2);
    }
  }
  __syncthreads();
}

__device__ void dif8192_pad_stage(cf* __restrict__ a, float sign){
  __syncthreads();
  #pragma unroll
  for (int g = 0; g < 8; g++){
    int w = (int)threadIdx.x + g * TPB;
    cf A0 = a[w], B0 = a[w + 2048];
    cf w1 = twid((float)w * (1.0f / 4096.0f), sign);
    cf w2 = cml(w1, w1);
    cf c1 = cml(A0, w1);
    cf d1 = cml(B0, cmk(-sign * w1.y, sign * w1.x));
    a[w]        = cad(A0, B0);
    a[w + 2048] = cml(csb(A0, B0), w2);
    a[w + 4096] = cad(c1, d1);
    a[w + 6144] = cml(csb(c1, d1), w2);
  }
}

__device__ __forceinline__ int brev13(int x){ return (int)(__brev((unsigned)x) >> 19); }

// ---------------- init atomic-max buffers ----------------
__global__ void k_init(unsigned* xmax, unsigned* ymax){
  int i = blockIdx.x * 256 + threadIdx.x;
  if (i < 2048){ xmax[i] = 0u; ymax[i] = 0u; }
}

// ---------------- transpose x (B,L,H)->(B,H,L), fused max|x| ----------------
__global__ __launch_bounds__(256) void k_transpose_x(const float* __restrict__ x,
                                                     float* __restrict__ xT,
                                                     unsigned* __restrict__ xmax){
  __shared__ float tile[64][65];
  __shared__ float red[64][4];
  int b = blockIdx.z;
  int t0 = blockIdx.x * 64;
  int h0 = blockIdx.y * 64;
  int hc = threadIdx.x & 63, tg = threadIdx.x >> 6;
  float pmax = 0.0f;
  #pragma unroll
  for (int q = 0; q < 16; q++){
    int tr = tg + q * 4;
    float v = x[((size_t)(b * 4096 + t0 + tr)) * 256 + h0 + hc];
    tile[tr][hc] = v;
    pmax = fmaxf(pmax, fabsf(v));
  }
  red[hc][tg] = pmax;
  __syncthreads();
  if (threadIdx.x < 64){
    float m = fmaxf(fmaxf(red[threadIdx.x][0], red[threadIdx.x][1]),
                    fmaxf(red[threadIdx.x][2], red[threadIdx.x][3]));
    atomicMax(&xmax[b * 256 + h0 + threadIdx.x], __float_as_uint(m));
  }
  #pragma unroll
  for (int q = 0; q < 16; q++){
    int hr = tg + q * 4;
    xT[((size_t)(b * 256 + h0 + hr)) * 4096 + t0 + hc] = tile[hc][hr];
  }
}

// ---------------- W -> bf16 hi/lo planes ----------------
__global__ void k_wsplit(const float* __restrict__ W, ushort* __restrict__ Wh, ushort* __restrict__ Wl){
  int i = blockIdx.x * 256 + threadIdx.x;
  ushort h, l;
  bfsplit(W[i], &h, &l);
  Wh[i] = h; Wl[i] = l;
}

// ---------------- Cauchy / generating function ----------------
__global__ __launch_bounds__(256) void k_cauchy(
    const float* __restrict__ Lr, const float* __restrict__ Li,
    const float* __restrict__ Pr, const float* __restrict__ Pi,
    const float* __restrict__ Qr, const float* __restrict__ Qi,
    const float* __restrict__ Br, const float* __restrict__ Bi,
    const float* __restrict__ Cr, const float* __restrict__ Ci,
    const float* __restrict__ stepp, cf* __restrict__ A)
{
  __shared__ cf sLam[64], sB[64], sP[64], sQB[64], sQP[64];
  __shared__ cf sInv[64][16];
  __shared__ cf sWood[16], sC[16], sG[16];
  int tid = threadIdx.x;
  int l0 = blockIdx.x * 16;
  float stepv = fmaxf(stepp[0], 1e-6f);
  if (tid < 64){
    cf lam = cmk(Lr[tid], Li[tid]);
    cf b = cmk(Br[tid], Bi[tid]);
    cf p = cmk(Pr[tid], Pi[tid]);
    cf q = cmk(Qr[tid], Qi[tid]);
    sLam[tid] = lam; sB[tid] = b; sP[tid] = p;
    sQB[tid] = cml(q, b);
    sQP[tid] = cml(q, p);
  }
  __syncthreads();
  if (tid < 16){
    int l = l0 + tid;
    float ang = -6.2831855f * ((float)l * (1.0f / 4096.0f));
    cf Om = cmk(cosf(ang), sinf(ang));
    cf den = cmk(1.0f + Om.x, Om.y);
    cf num = cmk(1.0f - Om.x, -Om.y);
    cf rden = crcp(den);
    sC[tid] = cml(cmk(2.0f, 0.0f), rden);
    cf g = cml(num, rden);
    float sc = 2.0f / stepv;
    sG[tid] = cmk(g.x * sc, g.y * sc);
  }
  __syncthreads();
  for (int it = tid; it < 1024; it += 256){
    int n = it >> 4, ll = it & 15;
    sInv[n][ll] = crcp(csb(sG[ll], sLam[n]));
  }
  __syncthreads();
  if (tid < 16){
    cf k10 = cmk(0,0), k11 = cmk(0,0);
    for (int n = 0; n < 64; n++){
      k10 = cad(k10, cml(sQB[n], sInv[n][tid]));
      k11 = cad(k11, cml(sQP[n], sInv[n][tid]));
    }
    sWood[tid] = cdv(k10, cmk(1.0f + k11.x, k11.y));
  }
  __syncthreads();
  int h = tid;
  cf a0[16], a1[16];
  #pragma unroll
  for (int ll = 0; ll < 16; ll++){ a0[ll] = cmk(0,0); a1[ll] = cmk(0,0); }
  for (int n = 0; n < 64; n++){
    cf cc = cmk(Cr[h * 64 + n], Ci[h * 64 + n]);
    cf cb = cml(cc, sB[n]);
    cf cp = cml(cc, sP[n]);
    #pragma unroll
    for (int ll = 0; ll < 16; ll++){
      cf iv = sInv[n][ll];
      a0[ll] = cad(a0[ll], cml(cb, iv));
      a1[ll] = cad(a1[ll], cml(cp, iv));
    }
  }
  cf* dst = A + (size_t)h * 4096 + l0;
  #pragma unroll
  for (int ll = 0; ll < 16; ll++){
    dst[ll] = cml(sC[ll], csb(a0[ll], cml(a1[ll], sWood[ll])));
  }
}

// ---------------- Kf pair tables (legacy LDS FFT; 128 blocks) ----------------
__global__ __launch_bounds__(256) void k_kf(const cf* __restrict__ A, float4* __restrict__ Sab){
  extern __shared__ cf c[];
  int hp = blockIdx.x, tid = threadIdx.x;
  const cf* a1p = A + (size_t)(2 * hp) * 4096;
  const cf* a2p = a1p + 4096;
  for (int l = tid; l < 4096; l += TPB){
    int r = (int)(__brev((unsigned)l) >> 20);
    cf u = a1p[l], v = a2p[l];
    c[r] = cmk(u.x - v.y, u.y + v.x);
  }
  fft_dit_r4<4096>(c, 1.0f);
  float k1[16], k2[16];
  #pragma unroll
  for (int q = 0; q < 16; q++){
    cf w = c[tid + q * 256];
    k1[q] = w.x * (1.0f / 4096.0f);
    k2[q] = w.y * (1.0f / 4096.0f);
  }
  __syncthreads();
  #pragma unroll
  for (int q = 0; q < 16; q++) c[tid + q * 256] = cmk(k1[q], k2[q]);
  dif8192_pad_stage(c, -1.0f);
  fft_dif_r4<8192, 512>(c, -1.0f);
  float4* rec = Sab + (size_t)hp * 4097;
  const float sc = 0.5f * 0.5f * (1.0f / 8192.0f);
  #pragma unroll
  for (int q8 = 0; q8 < 16; q8++){
    int t = tid + 256 * q8;
    int p = t << 1;
    int k = brev13(p);
    int qq = brev13((8192 - k) & 8191);
    cf Zp = c[p], Zq = c[qq];
    float K1x = (Zp.x + Zq.x), K1y = (Zp.y - Zq.y);
    float dx  = (Zp.x - Zq.x), dy  = (Zp.y + Zq.y);
    float K2x = dy, K2y = -dx;
    rec[t] = make_float4((K1x + K2x) * sc, (K1y + K2y) * sc,
                         (K1x - K2x) * sc, (K1y - K2y) * sc);
  }
  if (tid == 0){
    cf Z1 = c[1];
    float K1x = 2.0f * Z1.x, K2x = 2.0f * Z1.y;
    rec[4096] = make_float4((K1x + K2x) * sc, 0.0f, (K1x - K2x) * sc, 0.0f);
  }
}

// ---------------- conv: register-resident FFT, 2 channels packed per block ----------------
// LDS layout padded: idx(n) = n + 4*(n>>8)  (size 8320 cf = 65 KB)
__global__ __launch_bounds__(256) void k_conv(const float* __restrict__ xT,
                                              const float4* __restrict__ Sab,
                                              const float* __restrict__ Dp,
                                              ushort* __restrict__ y1h,
                                              ushort* __restrict__ y1l){
  __shared__ cf c[8320];
  int blk = blockIdx.x;
  int b = blk >> 7, hp = blk & 127;
  int t = threadIdx.x;
  const float* xs1 = xT + ((size_t)(b * 256 + 2 * hp)) * 4096;
  const float* xs2 = xs1 + 4096;
  cf v[32];
  // coalesced load; upper half (r>=16) is the zero pad
  #pragma unroll
  for (int r = 0; r < 16; r++){
    int n = t + 256 * r;
    v[r] = cmk(xs1[n], xs2[n]);
  }
  // ---- stage A (DIF, sign=-1): strides 4096(pad),2048,1024,512,256 ----
  #pragma unroll
  for (int r = 0; r < 16; r++)
    v[r + 16] = cml(v[r], twid((float)(t + 256 * r) * (1.0f / 4096.0f), -1.0f));
  #pragma unroll
  for (int r0 = 0; r0 < 4; r0++){
    cf w1 = twid((float)(t + 256 * r0) * (1.0f / 2048.0f), -1.0f);
    dif4q(v[r0], v[r0 + 4], v[r0 + 8], v[r0 + 12], w1, -1.0f);
    dif4q(v[r0 + 16], v[r0 + 20], v[r0 + 24], v[r0 + 28], w1, -1.0f);
  }
  {
    cf w1 = twid((float)t * (1.0f / 512.0f), -1.0f);
    #pragma unroll
    for (int r = 0; r < 32; r += 4)
      dif4q(v[r], v[r + 1], v[r + 2], v[r + 3], w1, -1.0f);
  }
  // ---- T1: write M0, read M1 ----
  #pragma unroll
  for (int r = 0; r < 32; r++) c[t + 260 * r] = v[r];
  __syncthreads();
  int Bq = t >> 3, sg = t & 7;
  int m1 = Bq * 260 + sg;
  #pragma unroll
  for (int u = 0; u < 32; u++) v[u] = c[m1 + 8 * u];
  // ---- stage B (DIF): strides 128,64,32,16,8 (offset o = sg + 8u) ----
  #pragma unroll
  for (int u = 0; u < 8; u++){
    cf w1 = twid((float)(sg + 8 * u) * (1.0f / 128.0f), -1.0f);
    dif4q(v[u], v[u + 8], v[u + 16], v[u + 24], w1, -1.0f);
  }
  #pragma unroll
  for (int p2 = 0; p2 < 2; p2++){
    cf w1 = twid((float)(sg + 8 * p2) * (1.0f / 32.0f), -1.0f);
    #pragma unroll
    for (int u0 = 0; u0 < 32; u0 += 8)
      dif4q(v[u0 + p2], v[u0 + p2 + 2], v[u0 + p2 + 4], v[u0 + p2 + 6], w1, -1.0f);
  }
  {
    cf tw = twid((float)sg * (1.0f / 8.0f), -1.0f);
    #pragma unroll
    for (int u = 0; u < 32; u += 2){
      cf lo = cad(v[u], v[u + 1]);
      cf hi = cml(csb(v[u], v[u + 1]), tw);
      v[u] = lo; v[u + 1] = hi;
    }
  }
  // ---- stage C (DIF strides 4,2,1 across sg via shuffles) ----
  {
    bool h4 = (sg & 4) != 0;
    cf tw4 = twid((float)(sg & 3) * 0.25f, -1.0f);
    #pragma unroll
    for (int u = 0; u < 32; u++){
      cf o = shflx(v[u], 4);
      v[u] = h4 ? cml(csb(o, v[u]), tw4) : cad(v[u], o);
    }
    bool h2 = (sg & 2) != 0;
    cf tw2 = twid((float)(sg & 1) * 0.5f, -1.0f);
    #pragma unroll
    for (int u = 0; u < 32; u++){
      cf o = shflx(v[u], 2);
      v[u] = h2 ? cml(csb(o, v[u]), tw2) : cad(v[u], o);
    }
    bool h1 = (sg & 1) != 0;
    #pragma unroll
    for (int u = 0; u < 32; u++){
      cf o = shflx(v[u], 1);
      v[u] = h1 ? csb(o, v[u]) : cad(v[u], o);
    }
  }
  #pragma unroll
  for (int u = 0; u < 32; u++) c[m1 + 8 * u] = v[u];
  __syncthreads();
  // ---- pointwise multiply (bitrev pairing, padded indices) ----
  const float4* rec = Sab + (size_t)hp * 4097;
  #pragma unroll
  for (int q8 = 0; q8 < 16; q8++){
    int th = t + 256 * q8;
    int p = th << 1;
    int k = brev13(p);
    int qq = brev13((8192 - k) & 8191);
    int pi = p + 4 * (p >> 8), qi = qq + 4 * (qq >> 8);
    cf Zp = c[pi], Zq = c[qi];
    float4 r0 = rec[th];
    cf Sap = cmk(r0.x, r0.y), Sbp = cmk(r0.z, r0.w);
    cf cZq = cmk(Zq.x, -Zq.y), cZp = cmk(Zp.x, -Zp.y);
    c[pi] = cad(cml(Zp, Sap), cml(cZq, Sbp));
    cf cSa = cmk(Sap.x, -Sap.y), cSb = cmk(Sbp.x, -Sbp.y);
    c[qi] = cad(cml(Zq, cSa), cml(cZp, cSb));
  }
  if (t == 0){
    float4 e = rec[4096];
    cf Z1 = c[1];
    c[1] = cad(cml(Z1, cmk(e.x, e.y)), cml(cmk(Z1.x, -Z1.y), cmk(e.z, e.w)));
  }
  __syncthreads();
  // ---- inverse: read M1 ----
  #pragma unroll
  for (int u = 0; u < 32; u++) v[u] = c[m1 + 8 * u];
  // ---- stage C' (DIT strides 1,2,4 across sg) ----
  {
    bool h1 = (sg & 1) != 0;
    #pragma unroll
    for (int u = 0; u < 32; u++){
      cf o = shflx(v[u], 1);
      v[u] = h1 ? csb(o, v[u]) : cad(v[u], o);
    }
    bool h2 = (sg & 2) != 0;
    cf w2 = twid((float)(sg & 1) * 0.5f, 1.0f);
    #pragma unroll
    for (int u = 0; u < 32; u++){
      cf o = shflx(v[u], 2);
      cf whv = cml(w2, h2 ? v[u] : o);
      v[u] = h2 ? csb(o, whv) : cad(v[u], whv);
    }
    bool h4 = (sg & 4) != 0;
    cf w4 = twid((float)(sg & 3) * 0.25f, 1.0f);
    #pragma unroll
    for (int u = 0; u < 32; u++){
      cf o = shflx(v[u], 4);
      cf whv = cml(w4, h4 ? v[u] : o);
      v[u] = h4 ? csb(o, whv) : cad(v[u], whv);
    }
  }
  // ---- stage B' (DIT strides 8,16,32,64,128) ----
  {
    cf tw = twid((float)sg * (1.0f / 8.0f), 1.0f);
    #pragma unroll
    for (int u = 0; u < 32; u += 2){
      cf tb = cml(v[u + 1], tw);
      cf a = v[u];
      v[u] = cad(a, tb);
      v[u + 1] = csb(a, tb);
    }
  }
  #pragma unroll
  for (int p2 = 0; p2 < 2; p2++){
    cf w1 = twid((float)(sg + 8 * p2) * (1.0f / 32.0f), 1.0f);
    #pragma unroll
    for (int u0 = 0; u0 < 32; u0 += 8)
      dit4q(v[u0 + p2], v[u0 + p2 + 2], v[u0 + p2 + 4], v[u0 + p2 + 6], w1, 1.0f);
  }
  #pragma unroll
  for (int u = 0; u < 8; u++){
    cf w1 = twid((float)(sg + 8 * u) * (1.0f / 128.0f), 1.0f);
    dit4q(v[u], v[u + 8], v[u + 16], v[u + 24], w1, 1.0f);
  }
  // ---- T1': write M1, read M0 ----
  #pragma unroll
  for (int u = 0; u < 32; u++) c[m1 + 8 * u] = v[u];
  __syncthreads();
  #pragma unroll
  for (int r = 0; r < 32; r++) v[r] = c[t + 260 * r];
  // ---- stage A' (DIT strides 256,512,1024,2048,4096) ----
  {
    cf tw = twid((float)t * (1.0f / 256.0f), 1.0f);
    #pragma unroll
    for (int r = 0; r < 32; r += 2){
      cf tb = cml(v[r + 1], tw);
      cf a = v[r];
      v[r] = cad(a, tb);
      v[r + 1] = csb(a, tb);
    }
  }
  #pragma unroll
  for (int p2 = 0; p2 < 2; p2++){
    cf w1 = twid((float)(t + 256 * p2) * (1.0f / 1024.0f), 1.0f);
    #pragma unroll
    for (int r0 = 0; r0 < 32; r0 += 8)
      dit4q(v[r0 + p2], v[r0 + p2 + 2], v[r0 + p2 + 4], v[r0 + p2 + 6], w1, 1.0f);
  }
  #pragma unroll
  for (int r0 = 0; r0 < 8; r0++){
    cf w1 = twid((float)(t + 256 * r0) * (1.0f / 4096.0f), 1.0f);
    dit4q(v[r0], v[r0 + 8], v[r0 + 16], v[r0 + 24], w1, 1.0f);
  }
  // ---- epilogue: gelu(h1 + D*x) -> bf16 split planes (only n < 4096) ----
  float Dv = Dp[0];
  size_t base = ((size_t)(b * 256 + 2 * hp)) * 4096;
  #pragma unroll
  for (int r = 0; r < 16; r++){
    int n = t + 256 * r;
    cf w = v[r];
    float z1 = geluf(fmaf(Dv, xs1[n], w.x));
    float z2 = geluf(fmaf(Dv, xs2[n], w.y));
    ushort h0, l0, h1u, l1;
    bfsplit(z1, &h0, &l0);
    bfsplit(z2, &h1u, &l1);
    y1h[base + n] = h0;        y1l[base + n] = l0;
    y1h[base + 4096 + n] = h1u; y1l[base + 4096 + n] = l1;
  }
}

// ---------------- MFMA split-bf16 GEMM + gelu + skip + LayerNorm + max|y| ----------------
__global__ __launch_bounds__(256, 3) void k_gemm_ln(
    const ushort* __restrict__ y1h, const ushort* __restrict__ y1l,
    const ushort* __restrict__ Wh, const ushort* __restrict__ Wl,
    const float* __restrict__ bfc, const float* __restrict__ x,
    const float* __restrict__ lng, const float* __restrict__ lnb,
    float* __restrict__ yout, unsigned* __restrict__ ymax)
{
  __shared__ ushort sY[2][64 * 40];
  __shared__ float red1[64][4], red2[64][4];
  int tid = threadIdx.x;
  int l = tid & 63;
  int w = tid >> 6;
  int blk = blockIdx.x;
  int b = blk >> 6;
  int t0 = (blk & 63) * 64;
  int g = l >> 4, cc = l & 15;

  f32x4 acc[4][4];
  #pragma unroll
  for (int m = 0; m < 4; m++)
    #pragma unroll
    for (int n = 0; n < 4; n++)
      acc[m][n] = (f32x4){0.0f, 0.0f, 0.0f, 0.0f};

  int kk = tid >> 3, ts = (tid & 7) * 8;

  #pragma unroll 1
  for (int kc = 0; kc < 256; kc += 32){
    __syncthreads();
    {
      size_t gb = ((size_t)(b * 256 + kc + kk)) * 4096 + t0 + ts;
      float4 vh = *(const float4*)(y1h + gb);
      float4 vl = *(const float4*)(y1l + gb);
      const ushort* ph = (const ushort*)&vh;
      const ushort* pl = (const ushort*)&vl;
      int kblk = kk >> 3, kin = kk & 7;
      #pragma unroll
      for (int e = 0; e < 8; e++){
        int t = ts + e;
        int idx = t * 40 + ((kblk ^ ((t >> 3) & 3)) << 3) + kin;
        sY[0][idx] = ph[e];
        sY[1][idx] = pl[e];
      }
    }
    __syncthreads();
    bf16x8 afh[4], afl[4];
    #pragma unroll
    for (int m = 0; m < 4; m++){
      int t = m * 16 + cc;
      int idx = t * 40 + ((g ^ ((t >> 3) & 3)) << 3);
      afh[m] = *(bf16x8*)&sY[0][idx];
      afl[m] = *(bf16x8*)&sY[1][idx];
    }
    #pragma unroll
    for (int n = 0; n < 4; n++){
      size_t wj = (size_t)(w * 64 + n * 16 + cc) * 256 + kc + g * 8;
      bf16x8 bh = *(const bf16x8*)(Wh + wj);
      bf16x8 bl = *(const bf16x8*)(Wl + wj);
      #pragma unroll
      for (int m = 0; m < 4; m++){
        acc[m][n] = __builtin_amdgcn_mfma_f32_16x16x32_bf16(afh[m], bh, acc[m][n], 0, 0, 0);
        acc[m][n] = __builtin_amdgcn_mfma_f32_16x16x32_bf16(afh[m], bl, acc[m][n], 0, 0, 0);
        acc[m][n] = __builtin_amdgcn_mfma_f32_16x16x32_bf16(afl[m], bh, acc[m][n], 0, 0, 0);
      }
    }
  }

  float bj[4], gj[4], lj[4];
  #pragma unroll
  for (int n = 0; n < 4; n++){
    int j = w * 64 + n * 16 + cc;
    bj[n] = bfc[j]; gj[n] = lng[j]; lj[n] = lnb[j];
  }
  #pragma unroll
  for (int m = 0; m < 4; m++){
    #pragma unroll
    for (int r = 0; r < 4; r++){
      int tl = m * 16 + g * 4 + r;
      size_t rowb = ((size_t)(b * 4096 + t0 + tl)) * 256;
      float ss = 0.0f, sq = 0.0f;
      #pragma unroll
      for (int n = 0; n < 4; n++){
        float z = geluf(acc[m][n][r] + bj[n]) + x[rowb + w * 64 + n * 16 + cc];
        acc[m][n][r] = z;
        ss += z; sq = fmaf(z, z, sq);
      }
      #pragma unroll
      for (int msk = 1; msk < 16; msk <<= 1){
        ss += __shfl_xor(ss, msk);
        sq += __shfl_xor(sq, msk);
      }
      if (cc == 0){ red1[tl][w] = ss; red2[tl][w] = sq; }
    }
  }
  __syncthreads();
  float jm[4] = {0.0f, 0.0f, 0.0f, 0.0f};
  #pragma unroll
  for (int m = 0; m < 4; m++){
    #pragma unroll
    for (int r = 0; r < 4; r++){
      int tl = m * 16 + g * 4 + r;
      float ts1 = red1[tl][0] + red1[tl][1] + red1[tl][2] + red1[tl][3];
      float ts2 = red2[tl][0] + red2[tl][1] + red2[tl][2] + red2[tl][3];
      float mu = ts1 * (1.0f / 256.0f);
      float var = ts2 * (1.0f / 256.0f) - mu * mu;
      float rstd = rsqrtf(var + 1e-5f);
      size_t rowb = ((size_t)(b * 4096 + t0 + tl)) * 256;
      #pragma unroll
      for (int n = 0; n < 4; n++){
        float yv = (acc[m][n][r] - mu) * rstd * gj[n] + lj[n];
        yout[rowb + w * 64 + n * 16 + cc] = yv;
        jm[n] = fmaxf(jm[n], fabsf(yv));
      }
    }
  }
  #pragma unroll
  for (int n = 0; n < 4; n++){
    jm[n] = fmaxf(jm[n], __shfl_xor(jm[n], 16));
    jm[n] = fmaxf(jm[n], __shfl_xor(jm[n], 32));
  }
  if (g == 0){
    #pragma unroll
    for (int n = 0; n < 4; n++)
      atomicMax(&ymax[b * 256 + w * 64 + n * 16 + cc], __float_as_uint(jm[n]));
  }
}

// ---------------- final ratio ----------------
__global__ void k_ratio(const unsigned* __restrict__ ymax, const unsigned* __restrict__ xmax,
                        float* __restrict__ out){
  int i = blockIdx.x * 256 + threadIdx.x;
  if (i < 2048){
    float ym = __uint_as_float(ymax[i]);
    float xm = __uint_as_float(xmax[i]);
    out[8388608 + i] = ym / (xm + 1e-6f);
  }
}

extern "C" void kernel_launch(void* const* d_in, const int* in_sizes, int n_in,
                              void* d_out, int out_size, void* d_ws, size_t ws_size,
                              hipStream_t stream)
{
  const float* x    = (const float*)d_in[0];
  const float* Lr   = (const float*)d_in[1];
  const float* Li   = (const float*)d_in[2];
  const float* Pr   = (const float*)d_in[3];
  const float* Pi   = (const float*)d_in[4];
  const float* Qr   = (const float*)d_in[5];
  const float* Qi   = (const float*)d_in[6];
  const float* Br   = (const float*)d_in[7];
  const float* Bi   = (const float*)d_in[8];
  const float* Cr   = (const float*)d_in[9];
  const float* Ci   = (const float*)d_in[10];
  const float* stp  = (const float*)d_in[11];
  const float* Dp   = (const float*)d_in[12];
  const float* Wfc  = (const float*)d_in[13];
  const float* bfc  = (const float*)d_in[14];
  const float* lng  = (const float*)d_in[15];
  const float* lnb  = (const float*)d_in[16];

  char* ws = (char*)d_ws;
  float*    xT   = (float*)(ws);                                   // 32 MB
  float4*   Sab  = (float4*)(ws + ((size_t)32 << 20));             // ~8.4 MB
  cf*       A    = (cf*)(ws + ((size_t)41 << 20));                 // 8 MB (dead after k_kf)
  ushort*   y1h  = (ushort*)(ws + ((size_t)41 << 20));             // 16 MB (overlays A)
  ushort*   y1l  = (ushort*)(ws + ((size_t)57 << 20));             // 16 MB
  ushort*   Wh   = (ushort*)(ws + ((size_t)73 << 20));             // 128 KB
  ushort*   Wl   = (ushort*)(ws + ((size_t)73 << 20) + (128u << 10));
  unsigned* xmax = (unsigned*)(ws + ((size_t)73 << 20) + (256u << 10));
  unsigned* ymax = xmax + 2048;

  k_init<<<8, 256, 0, stream>>>(xmax, ymax);
  dim3 gt(64, 4, 8);
  k_transpose_x<<<gt, 256, 0, stream>>>(x, xT, xmax);
  k_wsplit<<<256, 256, 0, stream>>>(Wfc, Wh, Wl);
  k_cauchy<<<256, 256, 0, stream>>>(Lr, Li, Pr, Pi, Qr, Qi, Br, Bi, Cr, Ci, stp, A);
  k_kf<<<128, 256, 65536, stream>>>(A, Sab);
  k_conv<<<1024, 256, 0, stream>>>(xT, Sab, Dp, y1h, y1l);
  k_gemm_ln<<<512, 256, 0, stream>>>(y1h, y1l, Wh, Wl, bfc, x, lng, lnb, (float*)d_out, ymax);
  k_ratio<<<8, 256, 0, stream>>>(ymax, xmax, (float*)d_out);
}